// Round 2
// baseline (1014.904 us; speedup 1.0000x reference)
//
#include <hip/hip_runtime.h>
#include <stdint.h>

typedef unsigned short u16;
typedef __attribute__((ext_vector_type(8))) short short8;
typedef __attribute__((ext_vector_type(4))) short short4v;
typedef __attribute__((ext_vector_type(4))) float floatx4;

#define T_DIM 2048
#define NH    16
#define HD    128
#define H_DIM 2048
#define I_DIM 8192
#define NCOL1 22528   // 3H + 2I
#define NCOL2 10240   // H + I
#define SPLITS 4
#define SLEN  (T_DIM / SPLITS)   // 512

__device__ __forceinline__ float bf2f(u16 b) {
  union { uint32_t u; float f; } x; x.u = ((uint32_t)b) << 16; return x.f;
}
__device__ __forceinline__ u16 f2bf(float f) {
  union { float f; uint32_t u; } x; x.f = f;
  uint32_t r = x.u + 0x7fffu + ((x.u >> 16) & 1u);
  return (u16)(r >> 16);
}

__device__ __forceinline__ void gl_lds16(const void* g, void* l) {
  __builtin_amdgcn_global_load_lds((const __attribute__((address_space(1))) void*)g,
                                   (__attribute__((address_space(3))) void*)l, 16, 0, 0);
}

__device__ __forceinline__ floatx4 mfma32(short8 a, short8 b, floatx4 c) {
  return __builtin_amdgcn_mfma_f32_16x16x32_bf16(a, b, c, 0, 0, 0);
}
__device__ __forceinline__ floatx4 mfma16(short4v a, short4v b, floatx4 c) {
#if __has_builtin(__builtin_amdgcn_mfma_f32_16x16x16bf16_1k)
  return __builtin_amdgcn_mfma_f32_16x16x16bf16_1k(a, b, c, 0, 0, 0);
#else
  asm volatile("v_mfma_f32_16x16x16_bf16 %0, %1, %2, %0" : "+v"(c) : "v"(a), "v"(b));
  return c;
#endif
}

// ---------------- RMSNorm + age override -> bf16 ----------------
__global__ __launch_bounds__(256) void rmsnorm_k(
    const float* __restrict__ x, const float* __restrict__ ages,
    const float* __restrict__ w, u16* __restrict__ xn) {
  int t = blockIdx.x, tid = threadIdx.x;
  const float* xr = x + (size_t)t * H_DIM;
  floatx4 a = *(const floatx4*)(xr + tid * 8);
  floatx4 b = *(const floatx4*)(xr + tid * 8 + 4);
  float ss = a[0]*a[0]+a[1]*a[1]+a[2]*a[2]+a[3]*a[3]
           + b[0]*b[0]+b[1]*b[1]+b[2]*b[2]+b[3]*b[3];
#pragma unroll
  for (int off = 32; off >= 1; off >>= 1) ss += __shfl_xor(ss, off);
  __shared__ float red[4];
  if ((tid & 63) == 0) red[tid >> 6] = ss;
  __syncthreads();
  float tot = red[0] + red[1] + red[2] + red[3];
  float rms = rsqrtf(tot * (1.0f / H_DIM) + 1e-6f);
  const float* wr = w + tid * 8;
  float v[8] = {a[0],a[1],a[2],a[3],b[0],b[1],b[2],b[3]};
  short8 o;
#pragma unroll
  for (int i = 0; i < 8; ++i) o[i] = (short)f2bf(v[i] * rms * wr[i]);
  if (tid == 255) {           // covers cols 2040..2047
    float ag = ages[t];
    o[6] = (short)f2bf(ag);
    o[7] = (short)f2bf(ag * ag);
  }
  *(short8*)(xn + (size_t)t * H_DIM + tid * 8) = o;
}

// ------------- fp32 (K,N) -> bf16 (N,K) transpose ---------------
__global__ __launch_bounds__(256) void transpose_f32_bf16(
    const float* __restrict__ in, u16* __restrict__ out, int K, int N) {
  __shared__ float tile[32][33];
  int n0 = blockIdx.x * 32, k0 = blockIdx.y * 32;
  int c = threadIdx.x & 31, r = threadIdx.x >> 5;
#pragma unroll
  for (int i = 0; i < 4; ++i) {
    int kk = r + i * 8;
    tile[c][kk] = in[(size_t)(k0 + kk) * N + n0 + c];
  }
  __syncthreads();
#pragma unroll
  for (int i = 0; i < 4; ++i) {
    int nn = r + i * 8;
    out[(size_t)(n0 + nn) * K + k0 + c] = f2bf(tile[nn][c]);
  }
}

// ------------- bf16 GEMM, B^T (N-major) input, 128x128 tile ------
template<int OUTF>
__global__ __launch_bounds__(256, 2) void gemm_bt(
    const u16* __restrict__ A, const u16* __restrict__ B,
    const float* __restrict__ bias, void* __restrict__ Cout,
    int M, int N, int K) {
  __shared__ u16 As[4096];
  __shared__ u16 Bs[4096];
  int nbn = N >> 7;
  int nwg = (M >> 7) * nbn;
  int bid = blockIdx.x;
  int swz = (bid & 7) * (nwg >> 3) + (bid >> 3);   // XCD swizzle (nwg%8==0)
  int bm = swz / nbn, bn = swz % nbn;
  int tid = threadIdx.x, lane = tid & 63;
  int wr = tid >> 7, wc = (tid >> 6) & 1;
  int lq = lane & 15, lg = lane >> 4;

  int r0 = tid >> 2, kc0 = (tid & 3) << 3;
  const u16* Ag0 = A + (size_t)(bm * 128 + r0) * K + kc0;
  const u16* Ag1 = Ag0 + (size_t)64 * K;
  const u16* Bg0 = B + (size_t)(bn * 128 + r0) * K + kc0;
  const u16* Bg1 = Bg0 + (size_t)64 * K;
  u16* As0 = As + tid * 8;
  u16* As1 = As + 2048 + tid * 8;
  u16* Bs0 = Bs + tid * 8;
  u16* Bs1 = Bs + 2048 + tid * 8;

  const u16* Ard = As + (wr * 64 + lq) * 32 + lg * 8;
  const u16* Brd = Bs + (wc * 64 + lq) * 32 + lg * 8;

  floatx4 acc[4][4] = {};

  for (int kt = 0; kt < K; kt += 32) {
    __syncthreads();
    gl_lds16(Ag0 + kt, As0);
    gl_lds16(Ag1 + kt, As1);
    gl_lds16(Bg0 + kt, Bs0);
    gl_lds16(Bg1 + kt, Bs1);
    __syncthreads();
    short8 af[4], bfr[4];
#pragma unroll
    for (int i = 0; i < 4; ++i) af[i]  = *(const short8*)(Ard + i * 512);
#pragma unroll
    for (int i = 0; i < 4; ++i) bfr[i] = *(const short8*)(Brd + i * 512);
#pragma unroll
    for (int mi = 0; mi < 4; ++mi)
#pragma unroll
      for (int ni = 0; ni < 4; ++ni)
        acc[mi][ni] = mfma32(af[mi], bfr[ni], acc[mi][ni]);
  }

#pragma unroll
  for (int mi = 0; mi < 4; ++mi) {
#pragma unroll
    for (int ni = 0; ni < 4; ++ni) {
      int col = bn * 128 + wc * 64 + ni * 16 + lq;
      float bv = bias[col];
#pragma unroll
      for (int j = 0; j < 4; ++j) {
        int row = bm * 128 + wr * 64 + mi * 16 + lg * 4 + j;
        float vv = acc[mi][ni][j] + bv;
        if (OUTF) ((float*)Cout)[(size_t)row * N + col] = vv;
        else      ((u16*)Cout)[(size_t)row * N + col]   = f2bf(vv);
      }
    }
  }
}

// ---- RoPE on q,k; split qkv; V stored transposed [h][d][t] ------
__global__ __launch_bounds__(256) void rope_split(
    const u16* __restrict__ tb, const float* __restrict__ sinp, const float* __restrict__ cosp,
    u16* __restrict__ qb, u16* __restrict__ kb, u16* __restrict__ vt) {
  __shared__ u16 vtile[32][130];
  int t0 = blockIdx.x * 32, h = blockIdx.y, tid = threadIdx.x;
  int r = tid >> 3, d0 = (tid & 7) << 4;
  int t = t0 + r;
  const u16* base = tb + (size_t)t * NCOL1 + 2 * I_DIM + h * HD + d0;
  const float* cp = cosp + (size_t)t * HD + d0;
  const float* sp = sinp + (size_t)t * HD + d0;
  float cv[16], sv[16];
#pragma unroll
  for (int i = 0; i < 16; i += 4) {
    *(floatx4*)(cv + i) = *(const floatx4*)(cp + i);
    *(floatx4*)(sv + i) = *(const floatx4*)(sp + i);
  }
#pragma unroll
  for (int s = 0; s < 2; ++s) {
    const u16* src = base + s * (NH * HD);
    short8 x0 = *(const short8*)src;
    short8 x1 = *(const short8*)(src + 8);
    float xf[16];
#pragma unroll
    for (int i = 0; i < 8; ++i) { xf[i] = bf2f((u16)x0[i]); xf[8 + i] = bf2f((u16)x1[i]); }
    short8 o0, o1;
#pragma unroll
    for (int i = 0; i < 8; i += 2) {
      o0[i]     = (short)f2bf(xf[i] * cv[i] - xf[i + 1] * sv[i]);
      o0[i + 1] = (short)f2bf(xf[i + 1] * cv[i + 1] + xf[i] * sv[i + 1]);
      o1[i]     = (short)f2bf(xf[8 + i] * cv[8 + i] - xf[9 + i] * sv[8 + i]);
      o1[i + 1] = (short)f2bf(xf[9 + i] * cv[9 + i] + xf[8 + i] * sv[9 + i]);
    }
    u16* dst = (s == 0 ? qb : kb) + ((size_t)h * T_DIM + t) * HD + d0;
    *(short8*)dst = o0;
    *(short8*)(dst + 8) = o1;
  }
  short8 v0 = *(const short8*)(base + 2 * NH * HD);
  short8 v1 = *(const short8*)(base + 2 * NH * HD + 8);
#pragma unroll
  for (int i = 0; i < 8; ++i) {
    vtile[r][d0 + i]     = (u16)v0[i];
    vtile[r][d0 + 8 + i] = (u16)v1[i];
  }
  __syncthreads();
  int d = tid >> 1, th = (tid & 1) << 4;
  short8 w0, w1;
#pragma unroll
  for (int i = 0; i < 8; ++i) {
    w0[i] = (short)vtile[th + i][d];
    w1[i] = (short)vtile[th + 8 + i][d];
  }
  u16* vdst = vt + ((size_t)h * HD + d) * T_DIM + t0 + th;
  *(short8*)vdst = w0;
  *(short8*)(vdst + 8) = w1;
}

// -------------------- silu(x1)*x2 -> comb[:, H:] -----------------
__global__ __launch_bounds__(256) void silu_mul(
    const u16* __restrict__ tb, u16* __restrict__ comb) {
  int idx = blockIdx.x * 256 + threadIdx.x;
  int t = idx >> 10;
  int j = (idx & 1023) << 3;
  const u16* p1 = tb + (size_t)t * NCOL1 + j;
  const u16* p2 = p1 + I_DIM;
  short8 a = *(const short8*)p1;
  short8 b = *(const short8*)p2;
  short8 o;
#pragma unroll
  for (int i = 0; i < 8; ++i) {
    float x1 = bf2f((u16)a[i]), x2 = bf2f((u16)b[i]);
    float s = x1 / (1.0f + __expf(-x1));
    o[i] = (short)f2bf(s * x2);
  }
  *(short8*)(comb + (size_t)t * NCOL2 + H_DIM + j) = o;
}

// ------ flash attention partial over s-range [sp*SLEN, (sp+1)*SLEN) ------
// S^T = mfma(K,Q); PV = mfma(V^T, P^T). Writes unnormalized o + (m,l).
__global__ __launch_bounds__(256) void attn_part(
    const u16* __restrict__ Q, const u16* __restrict__ K,
    const u16* __restrict__ V, const float* __restrict__ bias,
    float* __restrict__ po, float* __restrict__ pm, float* __restrict__ pl) {
  int h = blockIdx.x >> 5, qblk = blockIdx.x & 31;
  int sp = blockIdx.y;
  int wv = threadIdx.x >> 6, lane = threadIdx.x & 63;
  int lq = lane & 15, lg = lane >> 4;
  int q0 = qblk * 64 + wv * 16;
  const u16* Qp = Q + ((size_t)h * T_DIM + q0 + lq) * HD + lg * 8;
  const u16* Kh = K + (size_t)h * T_DIM * HD + lg * 8;
  const u16* Vh = V + ((size_t)h * HD + lq) * T_DIM + lg * 4;
  const float* Bp = bias + ((size_t)h * T_DIM + q0 + lq) * T_DIM + lg * 4;
  short8 qf[4];
#pragma unroll
  for (int t = 0; t < 4; ++t) qf[t] = *(const short8*)(Qp + t * 32);
  floatx4 o[8] = {};
  float m = -1e30f, l = 0.f;
  const float sc = 0.08838834764831845f;   // 1/sqrt(128)
  const int send = sp * SLEN + SLEN;
  for (int s0 = sp * SLEN; s0 < send; s0 += 32) {
    floatx4 st0 = {0.f,0.f,0.f,0.f}, st1 = {0.f,0.f,0.f,0.f};
    const u16* kp0 = Kh + (size_t)(s0 + lq) * HD;
    const u16* kp1 = kp0 + 16 * HD;
#pragma unroll
    for (int t = 0; t < 4; ++t) {
      st0 = mfma32(*(const short8*)(kp0 + t * 32), qf[t], st0);
      st1 = mfma32(*(const short8*)(kp1 + t * 32), qf[t], st1);
    }
    floatx4 b0 = *(const floatx4*)(Bp + s0);
    floatx4 b1 = *(const floatx4*)(Bp + s0 + 16);
    float p[8]; float tmax = -1e30f;
#pragma unroll
    for (int j = 0; j < 4; ++j) {
      p[j]     = st0[j] * sc + b0[j];
      p[4 + j] = st1[j] * sc + b1[j];
      tmax = fmaxf(tmax, fmaxf(p[j], p[4 + j]));
    }
    tmax = fmaxf(tmax, __shfl_xor(tmax, 16));
    tmax = fmaxf(tmax, __shfl_xor(tmax, 32));
    float mn = fmaxf(m, tmax);
    float alpha = __expf(m - mn);
    float rs = 0.f;
    short4v pb0, pb1;
#pragma unroll
    for (int j = 0; j < 4; ++j) {
      float e0 = __expf(p[j] - mn), e1 = __expf(p[4 + j] - mn);
      rs += e0 + e1;
      pb0[j] = (short)f2bf(e0);
      pb1[j] = (short)f2bf(e1);
    }
    rs += __shfl_xor(rs, 16);
    rs += __shfl_xor(rs, 32);
    l = l * alpha + rs; m = mn;
#pragma unroll
    for (int dt = 0; dt < 8; ++dt) o[dt] *= alpha;
#pragma unroll
    for (int dt = 0; dt < 8; ++dt) {
      short4v v0 = *(const short4v*)(Vh + (size_t)dt * 16 * T_DIM + s0);
      short4v v1 = *(const short4v*)(Vh + (size_t)dt * 16 * T_DIM + s0 + 16);
      o[dt] = mfma16(v0, pb0, o[dt]);
      o[dt] = mfma16(v1, pb1, o[dt]);
    }
  }
  size_t rb = (size_t)(sp * NH + h) * T_DIM + q0 + lq;
  float* op = po + rb * HD + lg * 4;
#pragma unroll
  for (int dt = 0; dt < 8; ++dt) *(floatx4*)(op + dt * 16) = o[dt];
  if (lg == 0) { pm[rb] = m; pl[rb] = l; }
}

// --------- combine split partials -> comb[:, :H] (bf16) ----------
__global__ __launch_bounds__(256) void attn_combine(
    const float* __restrict__ po, const float* __restrict__ pm,
    const float* __restrict__ pl, u16* __restrict__ comb) {
  int idx = blockIdx.x * 256 + threadIdx.x;   // over NH*T*HD/4
  int d4 = idx & 31;
  int t = (idx >> 5) & (T_DIM - 1);
  int h = idx >> 16;
  float ms[SPLITS];
  float M = -1e30f;
#pragma unroll
  for (int i = 0; i < SPLITS; ++i) {
    ms[i] = pm[(size_t)(i * NH + h) * T_DIM + t];
    M = fmaxf(M, ms[i]);
  }
  float den = 0.f;
  floatx4 num = {0.f, 0.f, 0.f, 0.f};
#pragma unroll
  for (int i = 0; i < SPLITS; ++i) {
    float w = __expf(ms[i] - M);
    den += w * pl[(size_t)(i * NH + h) * T_DIM + t];
    floatx4 ov = *(const floatx4*)(po + ((size_t)(i * NH + h) * T_DIM + t) * HD + d4 * 4);
#pragma unroll
    for (int j = 0; j < 4; ++j) num[j] += w * ov[j];
  }
  float inv = 1.0f / den;
  short4v r;
#pragma unroll
  for (int j = 0; j < 4; ++j) r[j] = (short)f2bf(num[j] * inv);
  *(short4v*)(comb + (size_t)t * NCOL2 + h * HD + d4 * 4) = r;
}

extern "C" void kernel_launch(void* const* d_in, const int* in_sizes, int n_in,
                              void* d_out, int out_size, void* d_ws, size_t ws_size,
                              hipStream_t stream) {
  (void)in_sizes; (void)n_in; (void)out_size; (void)ws_size;
  const float* x     = (const float*)d_in[0];
  const float* ages  = (const float*)d_in[1];
  const float* sinp  = (const float*)d_in[2];
  const float* cosp  = (const float*)d_in[3];
  const float* bias  = (const float*)d_in[4];
  const float* normw = (const float*)d_in[5];
  const float* w_in  = (const float*)d_in[6];
  const float* b_in  = (const float*)d_in[7];
  const float* w_out = (const float*)d_in[8];
  const float* b_out = (const float*)d_in[9];

  char* ws = (char*)d_ws;
  const size_t SZ_XN   = (size_t)T_DIM * H_DIM * 2;      //  8 MiB
  const size_t SZ_W1T  = (size_t)NCOL1 * H_DIM * 2;      //  88 MiB
  const size_t SZ_T    = (size_t)T_DIM * NCOL1 * 2;      //  88 MiB
  const size_t SZ_HEAD = (size_t)NH * T_DIM * HD * 2;    //   8 MiB
  u16* xn   = (u16*)(ws);
  u16* w1t  = (u16*)(ws + SZ_XN);
  u16* tb   = (u16*)(ws + SZ_XN + SZ_W1T);
  u16* qb   = (u16*)(ws + SZ_XN + SZ_W1T + SZ_T);
  u16* kb   = (u16*)(ws + SZ_XN + SZ_W1T + SZ_T + SZ_HEAD);
  u16* vt   = (u16*)(ws + SZ_XN + SZ_W1T + SZ_T + 2 * SZ_HEAD);
  u16* w2t  = (u16*)(ws + SZ_XN);                  // reuse w1t region (dead after GEMM1)
  u16* comb = (u16*)(ws + SZ_XN + (48ull << 20));  // also inside w1t region, disjoint from w2t
  // attention partials live in the tb region (dead after rope_split + silu_mul):
  float* po = (float*)tb;                                        // 64 MiB
  float* pm = (float*)(ws + SZ_XN + SZ_W1T + (64ull << 20));     // 512 KiB
  float* pl = pm + (size_t)SPLITS * NH * T_DIM;                  // 512 KiB

  rmsnorm_k<<<T_DIM, 256, 0, stream>>>(x, ages, normw, xn);
  transpose_f32_bf16<<<dim3(NCOL1 / 32, H_DIM / 32), 256, 0, stream>>>(w_in, w1t, H_DIM, NCOL1);
  gemm_bt<0><<<(T_DIM / 128) * (NCOL1 / 128), 256, 0, stream>>>(xn, w1t, b_in, tb, T_DIM, NCOL1, H_DIM);
  rope_split<<<dim3(T_DIM / 32, NH), 256, 0, stream>>>(tb, sinp, cosp, qb, kb, vt);
  silu_mul<<<(T_DIM * I_DIM) / (256 * 8), 256, 0, stream>>>(tb, comb);
  transpose_f32_bf16<<<dim3(H_DIM / 32, NCOL2 / 32), 256, 0, stream>>>(w_out, w2t, NCOL2, H_DIM);
  attn_part<<<dim3(NH * (T_DIM / 64), SPLITS), 256, 0, stream>>>(qb, kb, vt, bias, po, pm, pl);
  attn_combine<<<(NH * T_DIM * HD / 4) / 256, 256, 0, stream>>>(po, pm, pl, comb);
  gemm_bt<1><<<(T_DIM / 128) * (H_DIM / 128), 256, 0, stream>>>(comb, w2t, b_out, d_out, T_DIM, H_DIM, NCOL2);
}

// Round 3
// 975.537 us; speedup vs baseline: 1.0404x; 1.0404x over previous
//
#include <hip/hip_runtime.h>
#include <stdint.h>

typedef unsigned short u16;
typedef __attribute__((ext_vector_type(8))) short short8;
typedef __attribute__((ext_vector_type(4))) short short4v;
typedef __attribute__((ext_vector_type(4))) float floatx4;

#define T_DIM 2048
#define NH    16
#define HD    128
#define H_DIM 2048
#define I_DIM 8192
#define NCOL1 22528   // 3H + 2I
#define NCOL2 10240   // H + I
#define SPLITS 2
#define SLEN  (T_DIM / SPLITS)   // 1024

__device__ __forceinline__ float bf2f(u16 b) {
  union { uint32_t u; float f; } x; x.u = ((uint32_t)b) << 16; return x.f;
}
__device__ __forceinline__ u16 f2bf(float f) {
  union { float f; uint32_t u; } x; x.f = f;
  uint32_t r = x.u + 0x7fffu + ((x.u >> 16) & 1u);
  return (u16)(r >> 16);
}

__device__ __forceinline__ void gl_lds16(const void* g, void* l) {
  __builtin_amdgcn_global_load_lds((const __attribute__((address_space(1))) void*)g,
                                   (__attribute__((address_space(3))) void*)l, 16, 0, 0);
}

__device__ __forceinline__ floatx4 mfma32(short8 a, short8 b, floatx4 c) {
  return __builtin_amdgcn_mfma_f32_16x16x32_bf16(a, b, c, 0, 0, 0);
}
__device__ __forceinline__ floatx4 mfma16(short4v a, short4v b, floatx4 c) {
#if __has_builtin(__builtin_amdgcn_mfma_f32_16x16x16bf16_1k)
  return __builtin_amdgcn_mfma_f32_16x16x16bf16_1k(a, b, c, 0, 0, 0);
#else
  asm volatile("v_mfma_f32_16x16x16_bf16 %0, %1, %2, %0" : "+v"(c) : "v"(a), "v"(b));
  return c;
#endif
}

// ---------------- RMSNorm + age override -> bf16 ----------------
__global__ __launch_bounds__(256) void rmsnorm_k(
    const float* __restrict__ x, const float* __restrict__ ages,
    const float* __restrict__ w, u16* __restrict__ xn) {
  int t = blockIdx.x, tid = threadIdx.x;
  const float* xr = x + (size_t)t * H_DIM;
  floatx4 a = *(const floatx4*)(xr + tid * 8);
  floatx4 b = *(const floatx4*)(xr + tid * 8 + 4);
  float ss = a[0]*a[0]+a[1]*a[1]+a[2]*a[2]+a[3]*a[3]
           + b[0]*b[0]+b[1]*b[1]+b[2]*b[2]+b[3]*b[3];
#pragma unroll
  for (int off = 32; off >= 1; off >>= 1) ss += __shfl_xor(ss, off);
  __shared__ float red[4];
  if ((tid & 63) == 0) red[tid >> 6] = ss;
  __syncthreads();
  float tot = red[0] + red[1] + red[2] + red[3];
  float rms = rsqrtf(tot * (1.0f / H_DIM) + 1e-6f);
  const float* wr = w + tid * 8;
  float v[8] = {a[0],a[1],a[2],a[3],b[0],b[1],b[2],b[3]};
  short8 o;
#pragma unroll
  for (int i = 0; i < 8; ++i) o[i] = (short)f2bf(v[i] * rms * wr[i]);
  if (tid == 255) {           // covers cols 2040..2047
    float ag = ages[t];
    o[6] = (short)f2bf(ag);
    o[7] = (short)f2bf(ag * ag);
  }
  *(short8*)(xn + (size_t)t * H_DIM + tid * 8) = o;
}

// ------------- fp32 (K,N) -> bf16 (N,K) transpose ---------------
__global__ __launch_bounds__(256) void transpose_f32_bf16(
    const float* __restrict__ in, u16* __restrict__ out, int K, int N) {
  __shared__ float tile[32][33];
  int n0 = blockIdx.x * 32, k0 = blockIdx.y * 32;
  int c = threadIdx.x & 31, r = threadIdx.x >> 5;
#pragma unroll
  for (int i = 0; i < 4; ++i) {
    int kk = r + i * 8;
    tile[c][kk] = in[(size_t)(k0 + kk) * N + n0 + c];
  }
  __syncthreads();
#pragma unroll
  for (int i = 0; i < 4; ++i) {
    int nn = r + i * 8;
    out[(size_t)(n0 + nn) * K + k0 + c] = f2bf(tile[nn][c]);
  }
}

// ------------- bf16 GEMM, B^T (N-major) input, 128x128 tile ------
template<int OUTF>
__global__ __launch_bounds__(256, 2) void gemm_bt(
    const u16* __restrict__ A, const u16* __restrict__ B,
    const float* __restrict__ bias, void* __restrict__ Cout,
    int M, int N, int K) {
  __shared__ u16 As[4096];
  __shared__ u16 Bs[4096];
  int nbn = N >> 7;
  int nwg = (M >> 7) * nbn;
  int bid = blockIdx.x;
  int swz = (bid & 7) * (nwg >> 3) + (bid >> 3);   // XCD swizzle (nwg%8==0)
  int bm = swz / nbn, bn = swz % nbn;
  int tid = threadIdx.x, lane = tid & 63;
  int wr = tid >> 7, wc = (tid >> 6) & 1;
  int lq = lane & 15, lg = lane >> 4;

  int r0 = tid >> 2, kc0 = (tid & 3) << 3;
  const u16* Ag0 = A + (size_t)(bm * 128 + r0) * K + kc0;
  const u16* Ag1 = Ag0 + (size_t)64 * K;
  const u16* Bg0 = B + (size_t)(bn * 128 + r0) * K + kc0;
  const u16* Bg1 = Bg0 + (size_t)64 * K;
  u16* As0 = As + tid * 8;
  u16* As1 = As + 2048 + tid * 8;
  u16* Bs0 = Bs + tid * 8;
  u16* Bs1 = Bs + 2048 + tid * 8;

  const u16* Ard = As + (wr * 64 + lq) * 32 + lg * 8;
  const u16* Brd = Bs + (wc * 64 + lq) * 32 + lg * 8;

  floatx4 acc[4][4] = {};

  for (int kt = 0; kt < K; kt += 32) {
    __syncthreads();
    gl_lds16(Ag0 + kt, As0);
    gl_lds16(Ag1 + kt, As1);
    gl_lds16(Bg0 + kt, Bs0);
    gl_lds16(Bg1 + kt, Bs1);
    __syncthreads();
    short8 af[4], bfr[4];
#pragma unroll
    for (int i = 0; i < 4; ++i) af[i]  = *(const short8*)(Ard + i * 512);
#pragma unroll
    for (int i = 0; i < 4; ++i) bfr[i] = *(const short8*)(Brd + i * 512);
#pragma unroll
    for (int mi = 0; mi < 4; ++mi)
#pragma unroll
      for (int ni = 0; ni < 4; ++ni)
        acc[mi][ni] = mfma32(af[mi], bfr[ni], acc[mi][ni]);
  }

#pragma unroll
  for (int mi = 0; mi < 4; ++mi) {
#pragma unroll
    for (int ni = 0; ni < 4; ++ni) {
      int col = bn * 128 + wc * 64 + ni * 16 + lq;
      float bv = bias[col];
#pragma unroll
      for (int j = 0; j < 4; ++j) {
        int row = bm * 128 + wr * 64 + mi * 16 + lg * 4 + j;
        float vv = acc[mi][ni][j] + bv;
        if (OUTF) ((float*)Cout)[(size_t)row * N + col] = vv;
        else      ((u16*)Cout)[(size_t)row * N + col]   = f2bf(vv);
      }
    }
  }
}

// ---- RoPE on q,k; split qkv; V stored transposed [h][d][t] ------
__global__ __launch_bounds__(256) void rope_split(
    const u16* __restrict__ tb, const float* __restrict__ sinp, const float* __restrict__ cosp,
    u16* __restrict__ qb, u16* __restrict__ kb, u16* __restrict__ vt) {
  __shared__ u16 vtile[32][130];
  int t0 = blockIdx.x * 32, h = blockIdx.y, tid = threadIdx.x;
  int r = tid >> 3, d0 = (tid & 7) << 4;
  int t = t0 + r;
  const u16* base = tb + (size_t)t * NCOL1 + 2 * I_DIM + h * HD + d0;
  const float* cp = cosp + (size_t)t * HD + d0;
  const float* sp = sinp + (size_t)t * HD + d0;
  float cv[16], sv[16];
#pragma unroll
  for (int i = 0; i < 16; i += 4) {
    *(floatx4*)(cv + i) = *(const floatx4*)(cp + i);
    *(floatx4*)(sv + i) = *(const floatx4*)(sp + i);
  }
#pragma unroll
  for (int s = 0; s < 2; ++s) {
    const u16* src = base + s * (NH * HD);
    short8 x0 = *(const short8*)src;
    short8 x1 = *(const short8*)(src + 8);
    float xf[16];
#pragma unroll
    for (int i = 0; i < 8; ++i) { xf[i] = bf2f((u16)x0[i]); xf[8 + i] = bf2f((u16)x1[i]); }
    short8 o0, o1;
#pragma unroll
    for (int i = 0; i < 8; i += 2) {
      o0[i]     = (short)f2bf(xf[i] * cv[i] - xf[i + 1] * sv[i]);
      o0[i + 1] = (short)f2bf(xf[i + 1] * cv[i + 1] + xf[i] * sv[i + 1]);
      o1[i]     = (short)f2bf(xf[8 + i] * cv[8 + i] - xf[9 + i] * sv[8 + i]);
      o1[i + 1] = (short)f2bf(xf[9 + i] * cv[9 + i] + xf[8 + i] * sv[9 + i]);
    }
    u16* dst = (s == 0 ? qb : kb) + ((size_t)h * T_DIM + t) * HD + d0;
    *(short8*)dst = o0;
    *(short8*)(dst + 8) = o1;
  }
  short8 v0 = *(const short8*)(base + 2 * NH * HD);
  short8 v1 = *(const short8*)(base + 2 * NH * HD + 8);
#pragma unroll
  for (int i = 0; i < 8; ++i) {
    vtile[r][d0 + i]     = (u16)v0[i];
    vtile[r][d0 + 8 + i] = (u16)v1[i];
  }
  __syncthreads();
  int d = tid >> 1, th = (tid & 1) << 4;
  short8 w0, w1;
#pragma unroll
  for (int i = 0; i < 8; ++i) {
    w0[i] = (short)vtile[th + i][d];
    w1[i] = (short)vtile[th + 8 + i][d];
  }
  u16* vdst = vt + ((size_t)h * HD + d) * T_DIM + t0 + th;
  *(short8*)vdst = w0;
  *(short8*)(vdst + 8) = w1;
}

// -------------------- silu(x1)*x2 -> comb[:, H:] -----------------
__global__ __launch_bounds__(256) void silu_mul(
    const u16* __restrict__ tb, u16* __restrict__ comb) {
  int idx = blockIdx.x * 256 + threadIdx.x;
  int t = idx >> 10;
  int j = (idx & 1023) << 3;
  const u16* p1 = tb + (size_t)t * NCOL1 + j;
  const u16* p2 = p1 + I_DIM;
  short8 a = *(const short8*)p1;
  short8 b = *(const short8*)p2;
  short8 o;
#pragma unroll
  for (int i = 0; i < 8; ++i) {
    float x1 = bf2f((u16)a[i]), x2 = bf2f((u16)b[i]);
    float s = x1 / (1.0f + __expf(-x1));
    o[i] = (short)f2bf(s * x2);
  }
  *(short8*)(comb + (size_t)t * NCOL2 + H_DIM + j) = o;
}

// ------ flash attention partial over s-range [sp*SLEN, (sp+1)*SLEN) ------
// Fully software-pipelined: per 32-s body issues K(s+32), V(s+32), bias(s+64)
// (issue order matches consumption distance so FIFO vmcnt waits never drain
// the deeper prefetch), then computes QK/softmax/PV from regs loaded earlier.
__global__ __launch_bounds__(256) void attn_part(
    const u16* __restrict__ Q, const u16* __restrict__ K,
    const u16* __restrict__ V, const float* __restrict__ bias,
    float* __restrict__ po, float* __restrict__ pm, float* __restrict__ pl) {
  int h = blockIdx.x >> 5, qblk = blockIdx.x & 31;
  int sp = blockIdx.y;
  int wv = threadIdx.x >> 6, lane = threadIdx.x & 63;
  int lq = lane & 15, lg = lane >> 4;
  int q0 = qblk * 64 + wv * 16;
  const u16* Qp = Q + ((size_t)h * T_DIM + q0 + lq) * HD + lg * 8;
  const u16* Kh = K + (size_t)h * T_DIM * HD + lg * 8;
  const u16* Vh = V + ((size_t)h * HD + lq) * T_DIM + lg * 4;
  const float* Bp = bias + ((size_t)h * T_DIM + q0 + lq) * T_DIM + lg * 4;
  short8 qf[4];
#pragma unroll
  for (int t = 0; t < 4; ++t) qf[t] = *(const short8*)(Qp + t * 32);
  floatx4 o[8] = {};
  float m = -1e30f, l = 0.f;
  const float sc = 0.08838834764831845f;   // 1/sqrt(128)
  const int sbeg = sp * SLEN, send = sbeg + SLEN;

  short8  kA[8], kB[8];
  short4v vA[16], vB[16];
  floatx4 bA0, bA1, bB0, bB1;
  {
    const u16* kp = Kh + (size_t)(sbeg + lq) * HD;
#pragma unroll
    for (int t = 0; t < 4; ++t) {
      kA[t]     = *(const short8*)(kp + t * 32);
      kA[4 + t] = *(const short8*)(kp + 16 * HD + t * 32);
    }
#pragma unroll
    for (int dt = 0; dt < 8; ++dt) {
      vA[dt]     = *(const short4v*)(Vh + (size_t)dt * 16 * T_DIM + sbeg);
      vA[8 + dt] = *(const short4v*)(Vh + (size_t)dt * 16 * T_DIM + sbeg + 16);
    }
    bA0 = *(const floatx4*)(Bp + sbeg);
    bA1 = *(const floatx4*)(Bp + sbeg + 16);
    bB0 = *(const floatx4*)(Bp + sbeg + 32);
    bB1 = *(const floatx4*)(Bp + sbeg + 48);
  }

  auto body = [&](int scur, short8* kc, short8* kn, short4v* vc, short4v* vn,
                  floatx4& b0, floatx4& b1) {
    // issue next-tile K and V (depth 1)
    int sn = scur + 32; if (sn >= send) sn = sbeg;
    const u16* kp = Kh + (size_t)(sn + lq) * HD;
#pragma unroll
    for (int t = 0; t < 4; ++t) {
      kn[t]     = *(const short8*)(kp + t * 32);
      kn[4 + t] = *(const short8*)(kp + 16 * HD + t * 32);
    }
#pragma unroll
    for (int dt = 0; dt < 8; ++dt) {
      vn[dt]     = *(const short4v*)(Vh + (size_t)dt * 16 * T_DIM + sn);
      vn[8 + dt] = *(const short4v*)(Vh + (size_t)dt * 16 * T_DIM + sn + 16);
    }
    // copy current bias out, issue bias prefetch (depth 2, youngest issue)
    floatx4 cb0 = b0, cb1 = b1;
    int sb = scur + 64; if (sb >= send) sb = sbeg;
    b0 = *(const floatx4*)(Bp + sb);
    b1 = *(const floatx4*)(Bp + sb + 16);
    // QK^T from regs loaded one body ago
    floatx4 st0 = {0.f,0.f,0.f,0.f}, st1 = {0.f,0.f,0.f,0.f};
#pragma unroll
    for (int t = 0; t < 4; ++t) {
      st0 = mfma32(kc[t],     qf[t], st0);
      st1 = mfma32(kc[4 + t], qf[t], st1);
    }
    float p[8]; float tmax = -1e30f;
#pragma unroll
    for (int j = 0; j < 4; ++j) {
      p[j]     = st0[j] * sc + cb0[j];
      p[4 + j] = st1[j] * sc + cb1[j];
      tmax = fmaxf(tmax, fmaxf(p[j], p[4 + j]));
    }
    tmax = fmaxf(tmax, __shfl_xor(tmax, 16));
    tmax = fmaxf(tmax, __shfl_xor(tmax, 32));
    float mn = fmaxf(m, tmax);
    float alpha = __expf(m - mn);
    float rs = 0.f;
    short4v pb0, pb1;
#pragma unroll
    for (int j = 0; j < 4; ++j) {
      float e0 = __expf(p[j] - mn), e1 = __expf(p[4 + j] - mn);
      rs += e0 + e1;
      pb0[j] = (short)f2bf(e0);
      pb1[j] = (short)f2bf(e1);
    }
    rs += __shfl_xor(rs, 16);
    rs += __shfl_xor(rs, 32);
    l = l * alpha + rs; m = mn;
#pragma unroll
    for (int dt = 0; dt < 8; ++dt) o[dt] *= alpha;
#pragma unroll
    for (int dt = 0; dt < 8; ++dt) {
      o[dt] = mfma16(vc[dt],     pb0, o[dt]);
      o[dt] = mfma16(vc[8 + dt], pb1, o[dt]);
    }
  };

  for (int s0 = sbeg; s0 < send; s0 += 64) {
    body(s0,      kA, kB, vA, vB, bA0, bA1);
    body(s0 + 32, kB, kA, vB, vA, bB0, bB1);
  }

  size_t rb = (size_t)(sp * NH + h) * T_DIM + q0 + lq;
  float* op = po + rb * HD + lg * 4;
#pragma unroll
  for (int dt = 0; dt < 8; ++dt) *(floatx4*)(op + dt * 16) = o[dt];
  if (lg == 0) { pm[rb] = m; pl[rb] = l; }
}

// --------- combine split partials -> comb[:, :H] (bf16) ----------
__global__ __launch_bounds__(256) void attn_combine(
    const float* __restrict__ po, const float* __restrict__ pm,
    const float* __restrict__ pl, u16* __restrict__ comb) {
  int idx = blockIdx.x * 256 + threadIdx.x;   // over NH*T*HD/4
  int d4 = idx & 31;
  int t = (idx >> 5) & (T_DIM - 1);
  int h = idx >> 16;
  float ms[SPLITS];
  float M = -1e30f;
#pragma unroll
  for (int i = 0; i < SPLITS; ++i) {
    ms[i] = pm[(size_t)(i * NH + h) * T_DIM + t];
    M = fmaxf(M, ms[i]);
  }
  float den = 0.f;
  floatx4 num = {0.f, 0.f, 0.f, 0.f};
#pragma unroll
  for (int i = 0; i < SPLITS; ++i) {
    float w = __expf(ms[i] - M);
    den += w * pl[(size_t)(i * NH + h) * T_DIM + t];
    floatx4 ov = *(const floatx4*)(po + ((size_t)(i * NH + h) * T_DIM + t) * HD + d4 * 4);
#pragma unroll
    for (int j = 0; j < 4; ++j) num[j] += w * ov[j];
  }
  float inv = 1.0f / den;
  short4v r;
#pragma unroll
  for (int j = 0; j < 4; ++j) r[j] = (short)f2bf(num[j] * inv);
  *(short4v*)(comb + (size_t)t * NCOL2 + h * HD + d4 * 4) = r;
}

extern "C" void kernel_launch(void* const* d_in, const int* in_sizes, int n_in,
                              void* d_out, int out_size, void* d_ws, size_t ws_size,
                              hipStream_t stream) {
  (void)in_sizes; (void)n_in; (void)out_size; (void)ws_size;
  const float* x     = (const float*)d_in[0];
  const float* ages  = (const float*)d_in[1];
  const float* sinp  = (const float*)d_in[2];
  const float* cosp  = (const float*)d_in[3];
  const float* bias  = (const float*)d_in[4];
  const float* normw = (const float*)d_in[5];
  const float* w_in  = (const float*)d_in[6];
  const float* b_in  = (const float*)d_in[7];
  const float* w_out = (const float*)d_in[8];
  const float* b_out = (const float*)d_in[9];

  char* ws = (char*)d_ws;
  const size_t SZ_XN   = (size_t)T_DIM * H_DIM * 2;      //  8 MiB
  const size_t SZ_W1T  = (size_t)NCOL1 * H_DIM * 2;      //  88 MiB
  const size_t SZ_T    = (size_t)T_DIM * NCOL1 * 2;      //  88 MiB
  const size_t SZ_HEAD = (size_t)NH * T_DIM * HD * 2;    //   8 MiB
  u16* xn   = (u16*)(ws);
  u16* w1t  = (u16*)(ws + SZ_XN);
  u16* tb   = (u16*)(ws + SZ_XN + SZ_W1T);
  u16* qb   = (u16*)(ws + SZ_XN + SZ_W1T + SZ_T);
  u16* kb   = (u16*)(ws + SZ_XN + SZ_W1T + SZ_T + SZ_HEAD);
  u16* vt   = (u16*)(ws + SZ_XN + SZ_W1T + SZ_T + 2 * SZ_HEAD);
  u16* w2t  = (u16*)(ws + SZ_XN);                  // reuse w1t region (dead after GEMM1)
  u16* comb = (u16*)(ws + SZ_XN + (48ull << 20));  // also inside w1t region, disjoint from w2t
  // attention partials live in the tb region (dead after rope_split + silu_mul):
  float* po = (float*)tb;                                        // 32 MiB
  float* pm = (float*)(ws + SZ_XN + SZ_W1T + (64ull << 20));     // 256 KiB
  float* pl = pm + (size_t)SPLITS * NH * T_DIM;                  // 256 KiB

  rmsnorm_k<<<T_DIM, 256, 0, stream>>>(x, ages, normw, xn);
  transpose_f32_bf16<<<dim3(NCOL1 / 32, H_DIM / 32), 256, 0, stream>>>(w_in, w1t, H_DIM, NCOL1);
  gemm_bt<0><<<(T_DIM / 128) * (NCOL1 / 128), 256, 0, stream>>>(xn, w1t, b_in, tb, T_DIM, NCOL1, H_DIM);
  rope_split<<<dim3(T_DIM / 32, NH), 256, 0, stream>>>(tb, sinp, cosp, qb, kb, vt);
  silu_mul<<<(T_DIM * I_DIM) / (256 * 8), 256, 0, stream>>>(tb, comb);
  transpose_f32_bf16<<<dim3(H_DIM / 32, NCOL2 / 32), 256, 0, stream>>>(w_out, w2t, NCOL2, H_DIM);
  attn_part<<<dim3(NH * (T_DIM / 64), SPLITS), 256, 0, stream>>>(qb, kb, vt, bias, po, pm, pl);
  attn_combine<<<(NH * T_DIM * HD / 4) / 256, 256, 0, stream>>>(po, pm, pl, comb);
  gemm_bt<1><<<(T_DIM / 128) * (H_DIM / 128), 256, 0, stream>>>(comb, w2t, b_out, d_out, T_DIM, H_DIM, NCOL2);
}

// Round 4
// 952.582 us; speedup vs baseline: 1.0654x; 1.0241x over previous
//
#include <hip/hip_runtime.h>
#include <stdint.h>

typedef unsigned short u16;
typedef __attribute__((ext_vector_type(8))) short short8;
typedef __attribute__((ext_vector_type(4))) short short4v;
typedef __attribute__((ext_vector_type(4))) float floatx4;

#define T_DIM 2048
#define NH    16
#define HD    128
#define H_DIM 2048
#define I_DIM 8192
#define NCOL1 22528   // 3H + 2I
#define NCOL2 10240   // H + I
#define PADW  1036    // LDS words per bias row (1024 + pad; %4==0, 2-way banks)

__device__ __forceinline__ float bf2f(u16 b) {
  union { uint32_t u; float f; } x; x.u = ((uint32_t)b) << 16; return x.f;
}
__device__ __forceinline__ u16 f2bf(float f) {
  union { float f; uint32_t u; } x; x.f = f;
  uint32_t r = x.u + 0x7fffu + ((x.u >> 16) & 1u);
  return (u16)(r >> 16);
}

__device__ __forceinline__ void gl_lds16(const void* g, void* l) {
  __builtin_amdgcn_global_load_lds((const __attribute__((address_space(1))) void*)g,
                                   (__attribute__((address_space(3))) void*)l, 16, 0, 0);
}

__device__ __forceinline__ floatx4 mfma32(short8 a, short8 b, floatx4 c) {
  return __builtin_amdgcn_mfma_f32_16x16x32_bf16(a, b, c, 0, 0, 0);
}
__device__ __forceinline__ floatx4 mfma16(short4v a, short4v b, floatx4 c) {
#if __has_builtin(__builtin_amdgcn_mfma_f32_16x16x16bf16_1k)
  return __builtin_amdgcn_mfma_f32_16x16x16bf16_1k(a, b, c, 0, 0, 0);
#else
  asm volatile("v_mfma_f32_16x16x16_bf16 %0, %1, %2, %0" : "+v"(c) : "v"(a), "v"(b));
  return c;
#endif
}

// ---------------- RMSNorm + age override -> bf16 ----------------
__global__ __launch_bounds__(256) void rmsnorm_k(
    const float* __restrict__ x, const float* __restrict__ ages,
    const float* __restrict__ w, u16* __restrict__ xn) {
  int t = blockIdx.x, tid = threadIdx.x;
  const float* xr = x + (size_t)t * H_DIM;
  floatx4 a = *(const floatx4*)(xr + tid * 8);
  floatx4 b = *(const floatx4*)(xr + tid * 8 + 4);
  float ss = a[0]*a[0]+a[1]*a[1]+a[2]*a[2]+a[3]*a[3]
           + b[0]*b[0]+b[1]*b[1]+b[2]*b[2]+b[3]*b[3];
#pragma unroll
  for (int off = 32; off >= 1; off >>= 1) ss += __shfl_xor(ss, off);
  __shared__ float red[4];
  if ((tid & 63) == 0) red[tid >> 6] = ss;
  __syncthreads();
  float tot = red[0] + red[1] + red[2] + red[3];
  float rms = rsqrtf(tot * (1.0f / H_DIM) + 1e-6f);
  const float* wr = w + tid * 8;
  float v[8] = {a[0],a[1],a[2],a[3],b[0],b[1],b[2],b[3]};
  short8 o;
#pragma unroll
  for (int i = 0; i < 8; ++i) o[i] = (short)f2bf(v[i] * rms * wr[i]);
  if (tid == 255) {           // covers cols 2040..2047
    float ag = ages[t];
    o[6] = (short)f2bf(ag);
    o[7] = (short)f2bf(ag * ag);
  }
  *(short8*)(xn + (size_t)t * H_DIM + tid * 8) = o;
}

// ------------- fp32 (K,N) -> bf16 (N,K) transpose ---------------
__global__ __launch_bounds__(256) void transpose_f32_bf16(
    const float* __restrict__ in, u16* __restrict__ out, int K, int N) {
  __shared__ float tile[32][33];
  int n0 = blockIdx.x * 32, k0 = blockIdx.y * 32;
  int c = threadIdx.x & 31, r = threadIdx.x >> 5;
#pragma unroll
  for (int i = 0; i < 4; ++i) {
    int kk = r + i * 8;
    tile[c][kk] = in[(size_t)(k0 + kk) * N + n0 + c];
  }
  __syncthreads();
#pragma unroll
  for (int i = 0; i < 4; ++i) {
    int nn = r + i * 8;
    out[(size_t)(n0 + nn) * K + k0 + c] = f2bf(tile[nn][c]);
  }
}

// ------------- bf16 GEMM, B^T (N-major) input, 128x128 tile ------
template<int OUTF>
__global__ __launch_bounds__(256, 2) void gemm_bt(
    const u16* __restrict__ A, const u16* __restrict__ B,
    const float* __restrict__ bias, void* __restrict__ Cout,
    int M, int N, int K) {
  __shared__ u16 As[4096];
  __shared__ u16 Bs[4096];
  int nbn = N >> 7;
  int nwg = (M >> 7) * nbn;
  int bid = blockIdx.x;
  int swz = (bid & 7) * (nwg >> 3) + (bid >> 3);   // XCD swizzle (nwg%8==0)
  int bm = swz / nbn, bn = swz % nbn;
  int tid = threadIdx.x, lane = tid & 63;
  int wr = tid >> 7, wc = (tid >> 6) & 1;
  int lq = lane & 15, lg = lane >> 4;

  int r0 = tid >> 2, kc0 = (tid & 3) << 3;
  const u16* Ag0 = A + (size_t)(bm * 128 + r0) * K + kc0;
  const u16* Ag1 = Ag0 + (size_t)64 * K;
  const u16* Bg0 = B + (size_t)(bn * 128 + r0) * K + kc0;
  const u16* Bg1 = Bg0 + (size_t)64 * K;
  u16* As0 = As + tid * 8;
  u16* As1 = As + 2048 + tid * 8;
  u16* Bs0 = Bs + tid * 8;
  u16* Bs1 = Bs + 2048 + tid * 8;

  const u16* Ard = As + (wr * 64 + lq) * 32 + lg * 8;
  const u16* Brd = Bs + (wc * 64 + lq) * 32 + lg * 8;

  floatx4 acc[4][4] = {};

  for (int kt = 0; kt < K; kt += 32) {
    __syncthreads();
    gl_lds16(Ag0 + kt, As0);
    gl_lds16(Ag1 + kt, As1);
    gl_lds16(Bg0 + kt, Bs0);
    gl_lds16(Bg1 + kt, Bs1);
    __syncthreads();
    short8 af[4], bfr[4];
#pragma unroll
    for (int i = 0; i < 4; ++i) af[i]  = *(const short8*)(Ard + i * 512);
#pragma unroll
    for (int i = 0; i < 4; ++i) bfr[i] = *(const short8*)(Brd + i * 512);
#pragma unroll
    for (int mi = 0; mi < 4; ++mi)
#pragma unroll
      for (int ni = 0; ni < 4; ++ni)
        acc[mi][ni] = mfma32(af[mi], bfr[ni], acc[mi][ni]);
  }

#pragma unroll
  for (int mi = 0; mi < 4; ++mi) {
#pragma unroll
    for (int ni = 0; ni < 4; ++ni) {
      int col = bn * 128 + wc * 64 + ni * 16 + lq;
      float bv = bias[col];
#pragma unroll
      for (int j = 0; j < 4; ++j) {
        int row = bm * 128 + wr * 64 + mi * 16 + lg * 4 + j;
        float vv = acc[mi][ni][j] + bv;
        if (OUTF) ((float*)Cout)[(size_t)row * N + col] = vv;
        else      ((u16*)Cout)[(size_t)row * N + col]   = f2bf(vv);
      }
    }
  }
}

// ---- RoPE on q,k; split qkv; V stored transposed [h][d][t] ------
__global__ __launch_bounds__(256) void rope_split(
    const u16* __restrict__ tb, const float* __restrict__ sinp, const float* __restrict__ cosp,
    u16* __restrict__ qb, u16* __restrict__ kb, u16* __restrict__ vt) {
  __shared__ u16 vtile[32][130];
  int t0 = blockIdx.x * 32, h = blockIdx.y, tid = threadIdx.x;
  int r = tid >> 3, d0 = (tid & 7) << 4;
  int t = t0 + r;
  const u16* base = tb + (size_t)t * NCOL1 + 2 * I_DIM + h * HD + d0;
  const float* cp = cosp + (size_t)t * HD + d0;
  const float* sp = sinp + (size_t)t * HD + d0;
  float cv[16], sv[16];
#pragma unroll
  for (int i = 0; i < 16; i += 4) {
    *(floatx4*)(cv + i) = *(const floatx4*)(cp + i);
    *(floatx4*)(sv + i) = *(const floatx4*)(sp + i);
  }
#pragma unroll
  for (int s = 0; s < 2; ++s) {
    const u16* src = base + s * (NH * HD);
    short8 x0 = *(const short8*)src;
    short8 x1 = *(const short8*)(src + 8);
    float xf[16];
#pragma unroll
    for (int i = 0; i < 8; ++i) { xf[i] = bf2f((u16)x0[i]); xf[8 + i] = bf2f((u16)x1[i]); }
    short8 o0, o1;
#pragma unroll
    for (int i = 0; i < 8; i += 2) {
      o0[i]     = (short)f2bf(xf[i] * cv[i] - xf[i + 1] * sv[i]);
      o0[i + 1] = (short)f2bf(xf[i + 1] * cv[i + 1] + xf[i] * sv[i + 1]);
      o1[i]     = (short)f2bf(xf[8 + i] * cv[8 + i] - xf[9 + i] * sv[8 + i]);
      o1[i + 1] = (short)f2bf(xf[9 + i] * cv[9 + i] + xf[8 + i] * sv[9 + i]);
    }
    u16* dst = (s == 0 ? qb : kb) + ((size_t)h * T_DIM + t) * HD + d0;
    *(short8*)dst = o0;
    *(short8*)(dst + 8) = o1;
  }
  short8 v0 = *(const short8*)(base + 2 * NH * HD);
  short8 v1 = *(const short8*)(base + 2 * NH * HD + 8);
#pragma unroll
  for (int i = 0; i < 8; ++i) {
    vtile[r][d0 + i]     = (u16)v0[i];
    vtile[r][d0 + 8 + i] = (u16)v1[i];
  }
  __syncthreads();
  int d = tid >> 1, th = (tid & 1) << 4;
  short8 w0, w1;
#pragma unroll
  for (int i = 0; i < 8; ++i) {
    w0[i] = (short)vtile[th + i][d];
    w1[i] = (short)vtile[th + 8 + i][d];
  }
  u16* vdst = vt + ((size_t)h * HD + d) * T_DIM + t0 + th;
  *(short8*)vdst = w0;
  *(short8*)(vdst + 8) = w1;
}

// -------------------- silu(x1)*x2 -> comb[:, H:] -----------------
__global__ __launch_bounds__(256) void silu_mul(
    const u16* __restrict__ tb, u16* __restrict__ comb) {
  int idx = blockIdx.x * 256 + threadIdx.x;
  int t = idx >> 10;
  int j = (idx & 1023) << 3;
  const u16* p1 = tb + (size_t)t * NCOL1 + j;
  const u16* p2 = p1 + I_DIM;
  short8 a = *(const short8*)p1;
  short8 b = *(const short8*)p2;
  short8 o;
#pragma unroll
  for (int i = 0; i < 8; ++i) {
    float x1 = bf2f((u16)a[i]), x2 = bf2f((u16)b[i]);
    float s = x1 / (1.0f + __expf(-x1));
    o[i] = (short)f2bf(s * x2);
  }
  *(short8*)(comb + (size_t)t * NCOL2 + H_DIM + j) = o;
}

// ---- fused flash attention, bias staged dense into LDS -----------
// block = (h, 16 q-rows). Per 1024-col s-tile: stage 16x1024 f32 bias tile
// into LDS (16 fully-contiguous 4KB row reads -> DRAM-friendly), then the 4
// waves each run online softmax over their own strided 32-col sub-bodies.
// Final 4-way (m,l,o) merge in LDS, write bf16 to comb.
__global__ __launch_bounds__(256) void attn_fused(
    const u16* __restrict__ Q, const u16* __restrict__ K,
    const u16* __restrict__ V, const float* __restrict__ bias,
    u16* __restrict__ comb) {
  __shared__ float lds[16 * PADW];   // 66,304 B; reused for the final merge
  int bid = blockIdx.x;
  int swz = (bid & 7) * 256 + (bid >> 3);   // 2048 blocks, bijective XCD swizzle
  int h = swz >> 7, qt = swz & 127;
  int q0 = qt * 16;
  int tid = threadIdx.x;
  int w = tid >> 6, lane = tid & 63;
  int lq = lane & 15, lg = lane >> 4;

  const u16* Qp = Q + ((size_t)h * T_DIM + q0 + lq) * HD + lg * 8;
  const u16* Kh = K + (size_t)h * T_DIM * HD + lg * 8;
  const u16* Vh = V + ((size_t)h * HD + lq) * T_DIM + lg * 4;
  const float* Bh = bias + ((size_t)h * T_DIM + q0) * T_DIM;

  short8 qf[4];
#pragma unroll
  for (int t = 0; t < 4; ++t) qf[t] = *(const short8*)(Qp + t * 32);

  floatx4 o[8] = {};
  float m = -1e30f, l = 0.f;
  const float sc = 0.08838834764831845f;   // 1/sqrt(128)

#pragma unroll
  for (int tile = 0; tile < 2; ++tile) {
    // ---- stage bias tile: 16 rows x 4KB contiguous each ----
#pragma unroll
    for (int r = 0; r < 16; ++r) {
      const float* src = Bh + (size_t)r * T_DIM + tile * 1024 + tid * 4;
      gl_lds16(src, &lds[r * PADW + tid * 4]);
    }
    __syncthreads();   // drains vmcnt -> tile resident
    // ---- each wave: 8 sub-bodies of 32 s, strided by 128 ----
#pragma unroll
    for (int sub = 0; sub < 8; ++sub) {
      int soff = sub * 128 + w * 32;          // offset within tile
      int s0 = tile * 1024 + soff;            // global s
      floatx4 st0 = {0.f,0.f,0.f,0.f}, st1 = {0.f,0.f,0.f,0.f};
      const u16* kp0 = Kh + (size_t)(s0 + lq) * HD;
      const u16* kp1 = kp0 + 16 * HD;
#pragma unroll
      for (int t = 0; t < 4; ++t) {
        st0 = mfma32(*(const short8*)(kp0 + t * 32), qf[t], st0);
        st1 = mfma32(*(const short8*)(kp1 + t * 32), qf[t], st1);
      }
      floatx4 b0 = *(const floatx4*)&lds[lq * PADW + soff + lg * 4];
      floatx4 b1 = *(const floatx4*)&lds[lq * PADW + soff + lg * 4 + 16];
      float p[8]; float tmax = -1e30f;
#pragma unroll
      for (int j = 0; j < 4; ++j) {
        p[j]     = st0[j] * sc + b0[j];
        p[4 + j] = st1[j] * sc + b1[j];
        tmax = fmaxf(tmax, fmaxf(p[j], p[4 + j]));
      }
      tmax = fmaxf(tmax, __shfl_xor(tmax, 16));
      tmax = fmaxf(tmax, __shfl_xor(tmax, 32));
      float mn = fmaxf(m, tmax);
      float alpha = __expf(m - mn);
      float rs = 0.f;
      short4v pb0, pb1;
#pragma unroll
      for (int j = 0; j < 4; ++j) {
        float e0 = __expf(p[j] - mn), e1 = __expf(p[4 + j] - mn);
        rs += e0 + e1;
        pb0[j] = (short)f2bf(e0);
        pb1[j] = (short)f2bf(e1);
      }
      rs += __shfl_xor(rs, 16);
      rs += __shfl_xor(rs, 32);
      l = l * alpha + rs; m = mn;
#pragma unroll
      for (int dt = 0; dt < 8; ++dt) o[dt] *= alpha;
#pragma unroll
      for (int dt = 0; dt < 8; ++dt) {
        short4v v0 = *(const short4v*)(Vh + (size_t)dt * 16 * T_DIM + s0);
        short4v v1 = *(const short4v*)(Vh + (size_t)dt * 16 * T_DIM + s0 + 16);
        o[dt] = mfma16(v0, pb0, o[dt]);
        o[dt] = mfma16(v1, pb1, o[dt]);
      }
    }
    __syncthreads();   // all waves done reading before restage/merge
  }

  // ---- in-block 4-way (m,l,o) merge via LDS ----
  // layout: o at [w*2112 + lq*132 + d], m at [8448 + w*16 + lq], l at [8512 + ...]
  if (lg == 0) { lds[8448 + w * 16 + lq] = m; lds[8512 + w * 16 + lq] = l; }
  __syncthreads();
  float M = -1e30f;
#pragma unroll
  for (int i = 0; i < 4; ++i) M = fmaxf(M, lds[8448 + i * 16 + lq]);
  float scale = __expf(m - M);
#pragma unroll
  for (int dt = 0; dt < 8; ++dt) {
    floatx4 so = o[dt] * scale;
    *(floatx4*)&lds[w * 2112 + lq * 132 + dt * 16 + lg * 4] = so;
  }
  __syncthreads();
  // final reduce + normalize + write: thread t -> row t>>4, d0 = (t&15)*8
  {
    int row = tid >> 4, d0 = (tid & 15) * 8;
    float M2 = -1e30f;
#pragma unroll
    for (int i = 0; i < 4; ++i) M2 = fmaxf(M2, lds[8448 + i * 16 + row]);
    float den = 0.f;
#pragma unroll
    for (int i = 0; i < 4; ++i)
      den += __expf(lds[8448 + i * 16 + row] - M2) * lds[8512 + i * 16 + row];
    float inv = 1.0f / den;
    short8 ov;
#pragma unroll
    for (int k = 0; k < 8; ++k) {
      float s = 0.f;
#pragma unroll
      for (int i = 0; i < 4; ++i) s += lds[i * 2112 + row * 132 + d0 + k];
      ov[k] = (short)f2bf(s * inv);
    }
    *(short8*)(comb + (size_t)(q0 + row) * NCOL2 + h * HD + d0) = ov;
  }
}

extern "C" void kernel_launch(void* const* d_in, const int* in_sizes, int n_in,
                              void* d_out, int out_size, void* d_ws, size_t ws_size,
                              hipStream_t stream) {
  (void)in_sizes; (void)n_in; (void)out_size; (void)ws_size;
  const float* x     = (const float*)d_in[0];
  const float* ages  = (const float*)d_in[1];
  const float* sinp  = (const float*)d_in[2];
  const float* cosp  = (const float*)d_in[3];
  const float* bias  = (const float*)d_in[4];
  const float* normw = (const float*)d_in[5];
  const float* w_in  = (const float*)d_in[6];
  const float* b_in  = (const float*)d_in[7];
  const float* w_out = (const float*)d_in[8];
  const float* b_out = (const float*)d_in[9];

  char* ws = (char*)d_ws;
  const size_t SZ_XN   = (size_t)T_DIM * H_DIM * 2;      //  8 MiB
  const size_t SZ_W1T  = (size_t)NCOL1 * H_DIM * 2;      //  88 MiB
  const size_t SZ_T    = (size_t)T_DIM * NCOL1 * 2;      //  88 MiB
  const size_t SZ_HEAD = (size_t)NH * T_DIM * HD * 2;    //   8 MiB
  u16* xn   = (u16*)(ws);
  u16* w1t  = (u16*)(ws + SZ_XN);
  u16* tb   = (u16*)(ws + SZ_XN + SZ_W1T);
  u16* qb   = (u16*)(ws + SZ_XN + SZ_W1T + SZ_T);
  u16* kb   = (u16*)(ws + SZ_XN + SZ_W1T + SZ_T + SZ_HEAD);
  u16* vt   = (u16*)(ws + SZ_XN + SZ_W1T + SZ_T + 2 * SZ_HEAD);
  u16* w2t  = (u16*)(ws + SZ_XN);                  // reuse w1t region (dead after GEMM1)
  u16* comb = (u16*)(ws + SZ_XN + (48ull << 20));  // also inside w1t region, disjoint from w2t

  rmsnorm_k<<<T_DIM, 256, 0, stream>>>(x, ages, normw, xn);
  transpose_f32_bf16<<<dim3(NCOL1 / 32, H_DIM / 32), 256, 0, stream>>>(w_in, w1t, H_DIM, NCOL1);
  gemm_bt<0><<<(T_DIM / 128) * (NCOL1 / 128), 256, 0, stream>>>(xn, w1t, b_in, tb, T_DIM, NCOL1, H_DIM);
  rope_split<<<dim3(T_DIM / 32, NH), 256, 0, stream>>>(tb, sinp, cosp, qb, kb, vt);
  silu_mul<<<(T_DIM * I_DIM) / (256 * 8), 256, 0, stream>>>(tb, comb);
  transpose_f32_bf16<<<dim3(H_DIM / 32, NCOL2 / 32), 256, 0, stream>>>(w_out, w2t, NCOL2, H_DIM);
  attn_fused<<<NH * (T_DIM / 16), 256, 0, stream>>>(qb, kb, vt, bias, comb);
  gemm_bt<1><<<(T_DIM / 128) * (H_DIM / 128), 256, 0, stream>>>(comb, w2t, b_out, d_out, T_DIM, H_DIM, NCOL2);
}

// Round 5
// 729.021 us; speedup vs baseline: 1.3921x; 1.3067x over previous
//
#include <hip/hip_runtime.h>
#include <stdint.h>

typedef unsigned short u16;
typedef __attribute__((ext_vector_type(8))) short short8;
typedef __attribute__((ext_vector_type(4))) short short4v;
typedef __attribute__((ext_vector_type(4))) float floatx4;

#define T_DIM 2048
#define NH    16
#define HD    128
#define H_DIM 2048
#define I_DIM 8192
#define NCOL1 22528   // 3H + 2I
#define NCOL2 10240   // H + I
#define PADW  1036    // LDS words per bias row (1024 + pad; %4==0, 2-way banks)

__device__ __forceinline__ float bf2f(u16 b) {
  union { uint32_t u; float f; } x; x.u = ((uint32_t)b) << 16; return x.f;
}
__device__ __forceinline__ u16 f2bf(float f) {
  union { float f; uint32_t u; } x; x.f = f;
  uint32_t r = x.u + 0x7fffu + ((x.u >> 16) & 1u);
  return (u16)(r >> 16);
}

__device__ __forceinline__ void gl_lds16(const void* g, void* l) {
  __builtin_amdgcn_global_load_lds((const __attribute__((address_space(1))) void*)g,
                                   (__attribute__((address_space(3))) void*)l, 16, 0, 0);
}

__device__ __forceinline__ floatx4 mfma32(short8 a, short8 b, floatx4 c) {
  return __builtin_amdgcn_mfma_f32_16x16x32_bf16(a, b, c, 0, 0, 0);
}
__device__ __forceinline__ floatx4 mfma16(short4v a, short4v b, floatx4 c) {
#if __has_builtin(__builtin_amdgcn_mfma_f32_16x16x16bf16_1k)
  return __builtin_amdgcn_mfma_f32_16x16x16bf16_1k(a, b, c, 0, 0, 0);
#else
  asm volatile("v_mfma_f32_16x16x16_bf16 %0, %1, %2, %0" : "+v"(c) : "v"(a), "v"(b));
  return c;
#endif
}

// ---------------- RMSNorm + age override -> bf16 ----------------
__global__ __launch_bounds__(256) void rmsnorm_k(
    const float* __restrict__ x, const float* __restrict__ ages,
    const float* __restrict__ w, u16* __restrict__ xn) {
  int t = blockIdx.x, tid = threadIdx.x;
  const float* xr = x + (size_t)t * H_DIM;
  floatx4 a = *(const floatx4*)(xr + tid * 8);
  floatx4 b = *(const floatx4*)(xr + tid * 8 + 4);
  float ss = a[0]*a[0]+a[1]*a[1]+a[2]*a[2]+a[3]*a[3]
           + b[0]*b[0]+b[1]*b[1]+b[2]*b[2]+b[3]*b[3];
#pragma unroll
  for (int off = 32; off >= 1; off >>= 1) ss += __shfl_xor(ss, off);
  __shared__ float red[4];
  if ((tid & 63) == 0) red[tid >> 6] = ss;
  __syncthreads();
  float tot = red[0] + red[1] + red[2] + red[3];
  float rms = rsqrtf(tot * (1.0f / H_DIM) + 1e-6f);
  const float* wr = w + tid * 8;
  float v[8] = {a[0],a[1],a[2],a[3],b[0],b[1],b[2],b[3]};
  short8 o;
#pragma unroll
  for (int i = 0; i < 8; ++i) o[i] = (short)f2bf(v[i] * rms * wr[i]);
  if (tid == 255) {           // covers cols 2040..2047
    float ag = ages[t];
    o[6] = (short)f2bf(ag);
    o[7] = (short)f2bf(ag * ag);
  }
  *(short8*)(xn + (size_t)t * H_DIM + tid * 8) = o;
}

// ------------- fp32 (K,N) -> bf16 (N,K) transpose ---------------
__global__ __launch_bounds__(256) void transpose_f32_bf16(
    const float* __restrict__ in, u16* __restrict__ out, int K, int N) {
  __shared__ float tile[32][33];
  int n0 = blockIdx.x * 32, k0 = blockIdx.y * 32;
  int c = threadIdx.x & 31, r = threadIdx.x >> 5;
#pragma unroll
  for (int i = 0; i < 4; ++i) {
    int kk = r + i * 8;
    tile[c][kk] = in[(size_t)(k0 + kk) * N + n0 + c];
  }
  __syncthreads();
#pragma unroll
  for (int i = 0; i < 4; ++i) {
    int nn = r + i * 8;
    out[(size_t)(n0 + nn) * K + k0 + c] = f2bf(tile[nn][c]);
  }
}

// ------------- bf16 GEMM, B^T (N-major) input, 128x128 tile ------
template<int OUTF>
__global__ __launch_bounds__(256, 2) void gemm_bt(
    const u16* __restrict__ A, const u16* __restrict__ B,
    const float* __restrict__ bias, void* __restrict__ Cout,
    int M, int N, int K) {
  __shared__ u16 As[4096];
  __shared__ u16 Bs[4096];
  int nbn = N >> 7;
  int nwg = (M >> 7) * nbn;
  int bid = blockIdx.x;
  int swz = (bid & 7) * (nwg >> 3) + (bid >> 3);   // XCD swizzle (nwg%8==0)
  int bm = swz / nbn, bn = swz % nbn;
  int tid = threadIdx.x, lane = tid & 63;
  int wr = tid >> 7, wc = (tid >> 6) & 1;
  int lq = lane & 15, lg = lane >> 4;

  int r0 = tid >> 2, kc0 = (tid & 3) << 3;
  const u16* Ag0 = A + (size_t)(bm * 128 + r0) * K + kc0;
  const u16* Ag1 = Ag0 + (size_t)64 * K;
  const u16* Bg0 = B + (size_t)(bn * 128 + r0) * K + kc0;
  const u16* Bg1 = Bg0 + (size_t)64 * K;
  u16* As0 = As + tid * 8;
  u16* As1 = As + 2048 + tid * 8;
  u16* Bs0 = Bs + tid * 8;
  u16* Bs1 = Bs + 2048 + tid * 8;

  const u16* Ard = As + (wr * 64 + lq) * 32 + lg * 8;
  const u16* Brd = Bs + (wc * 64 + lq) * 32 + lg * 8;

  floatx4 acc[4][4] = {};

  for (int kt = 0; kt < K; kt += 32) {
    __syncthreads();
    gl_lds16(Ag0 + kt, As0);
    gl_lds16(Ag1 + kt, As1);
    gl_lds16(Bg0 + kt, Bs0);
    gl_lds16(Bg1 + kt, Bs1);
    __syncthreads();
    short8 af[4], bfr[4];
#pragma unroll
    for (int i = 0; i < 4; ++i) af[i]  = *(const short8*)(Ard + i * 512);
#pragma unroll
    for (int i = 0; i < 4; ++i) bfr[i] = *(const short8*)(Brd + i * 512);
#pragma unroll
    for (int mi = 0; mi < 4; ++mi)
#pragma unroll
      for (int ni = 0; ni < 4; ++ni)
        acc[mi][ni] = mfma32(af[mi], bfr[ni], acc[mi][ni]);
  }

#pragma unroll
  for (int mi = 0; mi < 4; ++mi) {
#pragma unroll
    for (int ni = 0; ni < 4; ++ni) {
      int col = bn * 128 + wc * 64 + ni * 16 + lq;
      float bv = bias[col];
#pragma unroll
      for (int j = 0; j < 4; ++j) {
        int row = bm * 128 + wr * 64 + mi * 16 + lg * 4 + j;
        float vv = acc[mi][ni][j] + bv;
        if (OUTF) ((float*)Cout)[(size_t)row * N + col] = vv;
        else      ((u16*)Cout)[(size_t)row * N + col]   = f2bf(vv);
      }
    }
  }
}

// ---- RoPE on q,k; split qkv; K,V stored in MFMA-fragment order ----
// K_frag chunk (h, s16, t): 64 lanes x 8 elems; lane=(s&15)+16*lg holds
//   K[s16*16+(s&15)][t*32+lg*8+j], j=0..7.  chunk = 512 elems (1KB).
// V_frag chunk (h, s16, dp): lane=(d&15)+16*lg holds
//   V[s16*16+lg*4+j][dp*32+par*16+(d&15)] packed [par=0:4elem][par=1:4elem].
__global__ __launch_bounds__(256) void rope_split(
    const u16* __restrict__ tb, const float* __restrict__ sinp, const float* __restrict__ cosp,
    u16* __restrict__ qb, u16* __restrict__ kf, u16* __restrict__ vf) {
  __shared__ u16 vtile[32][130];
  int t0 = blockIdx.x * 32, h = blockIdx.y, tid = threadIdx.x;
  int r = tid >> 3, d0 = (tid & 7) << 4;
  int t = t0 + r;
  const u16* base = tb + (size_t)t * NCOL1 + 2 * I_DIM + h * HD + d0;
  const float* cp = cosp + (size_t)t * HD + d0;
  const float* sp = sinp + (size_t)t * HD + d0;
  float cv[16], sv[16];
#pragma unroll
  for (int i = 0; i < 16; i += 4) {
    *(floatx4*)(cv + i) = *(const floatx4*)(cp + i);
    *(floatx4*)(sv + i) = *(const floatx4*)(sp + i);
  }
#pragma unroll
  for (int s = 0; s < 2; ++s) {
    const u16* src = base + s * (NH * HD);
    short8 x0 = *(const short8*)src;
    short8 x1 = *(const short8*)(src + 8);
    float xf[16];
#pragma unroll
    for (int i = 0; i < 8; ++i) { xf[i] = bf2f((u16)x0[i]); xf[8 + i] = bf2f((u16)x1[i]); }
    short8 o0, o1;
#pragma unroll
    for (int i = 0; i < 8; i += 2) {
      o0[i]     = (short)f2bf(xf[i] * cv[i] - xf[i + 1] * sv[i]);
      o0[i + 1] = (short)f2bf(xf[i + 1] * cv[i + 1] + xf[i] * sv[i + 1]);
      o1[i]     = (short)f2bf(xf[8 + i] * cv[8 + i] - xf[9 + i] * sv[8 + i]);
      o1[i + 1] = (short)f2bf(xf[9 + i] * cv[9 + i] + xf[8 + i] * sv[9 + i]);
    }
    if (s == 0) {
      u16* dst = qb + ((size_t)h * T_DIM + t) * HD + d0;
      *(short8*)dst = o0;
      *(short8*)(dst + 8) = o1;
    } else {
      int s16 = t >> 4, tt = d0 >> 5, lg0 = (d0 >> 3) & 3;
      size_t cb = (((size_t)h * 128 + s16) * 4 + tt) * 512 + ((t & 15) + 16 * lg0) * 8;
      *(short8*)(kf + cb) = o0;          // lg0
      *(short8*)(kf + cb + 128) = o1;    // lg0+1
    }
  }
  short8 v0 = *(const short8*)(base + 2 * NH * HD);
  short8 v1 = *(const short8*)(base + 2 * NH * HD + 8);
#pragma unroll
  for (int i = 0; i < 8; ++i) {
    vtile[r][d0 + i]     = (u16)v0[i];
    vtile[r][d0 + 8 + i] = (u16)v1[i];
  }
  __syncthreads();
  {
    int d = tid >> 1, th = (tid & 1) << 4;
    int s16 = (t0 + th) >> 4;
    int dp = d >> 5, par = (d >> 4) & 1, lqv = d & 15;
    size_t cb = (((size_t)h * 128 + s16) * 4 + dp) * 512 + par * 4;
#pragma unroll
    for (int lg = 0; lg < 4; ++lg) {
      short4v g;
#pragma unroll
      for (int j = 0; j < 4; ++j) g[j] = (short)vtile[th + lg * 4 + j][d];
      *(short4v*)(vf + cb + (size_t)(lqv + 16 * lg) * 8) = g;
    }
  }
}

// -------------------- silu(x1)*x2 -> comb[:, H:] -----------------
__global__ __launch_bounds__(256) void silu_mul(
    const u16* __restrict__ tb, u16* __restrict__ comb) {
  int idx = blockIdx.x * 256 + threadIdx.x;
  int t = idx >> 10;
  int j = (idx & 1023) << 3;
  const u16* p1 = tb + (size_t)t * NCOL1 + j;
  const u16* p2 = p1 + I_DIM;
  short8 a = *(const short8*)p1;
  short8 b = *(const short8*)p2;
  short8 o;
#pragma unroll
  for (int i = 0; i < 8; ++i) {
    float x1 = bf2f((u16)a[i]), x2 = bf2f((u16)b[i]);
    float s = x1 / (1.0f + __expf(-x1));
    o[i] = (short)f2bf(s * x2);
  }
  *(short8*)(comb + (size_t)t * NCOL2 + H_DIM + j) = o;
}

// ---- fused flash attention; bias dense in LDS; K/V fragment-packed ----
__global__ __launch_bounds__(256) void attn_fused(
    const u16* __restrict__ Q, const u16* __restrict__ kf,
    const u16* __restrict__ vf, const float* __restrict__ bias,
    u16* __restrict__ comb) {
  __shared__ float lds[16 * PADW];   // 66,304 B; reused for the final merge
  int bid = blockIdx.x;
  int swz = (bid & 7) * 256 + (bid >> 3);   // 2048 blocks, bijective XCD swizzle
  int h = swz >> 7, qt = swz & 127;
  int q0 = qt * 16;
  int tid = threadIdx.x;
  int w = tid >> 6, lane = tid & 63;
  int lq = lane & 15, lg = lane >> 4;

  const u16* Qp = Q + ((size_t)h * T_DIM + q0 + lq) * HD + lg * 8;
  const u16* Kf = kf + ((size_t)h * 128) * 2048 + lane * 8;  // + s16*2048 + t*512
  const u16* Vf = vf + ((size_t)h * 128) * 2048 + lane * 8;  // + s16*2048 + dp*512
  const float* Bh = bias + ((size_t)h * T_DIM + q0) * T_DIM;

  short8 qf[4];
#pragma unroll
  for (int t = 0; t < 4; ++t) qf[t] = *(const short8*)(Qp + t * 32);

  floatx4 o[8] = {};
  float m = -1e30f, l = 0.f;
  const float sc = 0.08838834764831845f;   // 1/sqrt(128)

#pragma unroll
  for (int tile = 0; tile < 2; ++tile) {
    // ---- stage bias tile: 16 rows x 4KB contiguous each ----
#pragma unroll
    for (int r = 0; r < 16; ++r) {
      const float* src = Bh + (size_t)r * T_DIM + tile * 1024 + tid * 4;
      gl_lds16(src, &lds[r * PADW + tid * 4]);
    }
    __syncthreads();   // drains vmcnt -> tile resident
    // ---- each wave: 8 sub-bodies of 32 s, strided by 128 ----
#pragma unroll
    for (int sub = 0; sub < 8; ++sub) {
      int soff = sub * 128 + w * 32;          // offset within tile
      int s0 = tile * 1024 + soff;            // global s
      int s16a = s0 >> 4;
      const u16* ka = Kf + (size_t)s16a * 2048;
      floatx4 st0 = {0.f,0.f,0.f,0.f}, st1 = {0.f,0.f,0.f,0.f};
#pragma unroll
      for (int t = 0; t < 4; ++t) {
        st0 = mfma32(*(const short8*)(ka + t * 512), qf[t], st0);
        st1 = mfma32(*(const short8*)(ka + 2048 + t * 512), qf[t], st1);
      }
      floatx4 b0 = *(const floatx4*)&lds[lq * PADW + soff + lg * 4];
      floatx4 b1 = *(const floatx4*)&lds[lq * PADW + soff + lg * 4 + 16];
      float p[8]; float tmax = -1e30f;
#pragma unroll
      for (int j = 0; j < 4; ++j) {
        p[j]     = st0[j] * sc + b0[j];
        p[4 + j] = st1[j] * sc + b1[j];
        tmax = fmaxf(tmax, fmaxf(p[j], p[4 + j]));
      }
      tmax = fmaxf(tmax, __shfl_xor(tmax, 16));
      tmax = fmaxf(tmax, __shfl_xor(tmax, 32));
      float mn = fmaxf(m, tmax);
      float alpha = __expf(m - mn);
      float rs = 0.f;
      short4v pb0, pb1;
#pragma unroll
      for (int j = 0; j < 4; ++j) {
        float e0 = __expf(p[j] - mn), e1 = __expf(p[4 + j] - mn);
        rs += e0 + e1;
        pb0[j] = (short)f2bf(e0);
        pb1[j] = (short)f2bf(e1);
      }
      rs += __shfl_xor(rs, 16);
      rs += __shfl_xor(rs, 32);
      l = l * alpha + rs; m = mn;
#pragma unroll
      for (int dt = 0; dt < 8; ++dt) o[dt] *= alpha;
      const u16* vb = Vf + (size_t)s16a * 2048;
#pragma unroll
      for (int dp = 0; dp < 4; ++dp) {
        short8 wa = *(const short8*)(vb + dp * 512);
        short8 wb = *(const short8*)(vb + 2048 + dp * 512);
        short4v a0 = {wa[0], wa[1], wa[2], wa[3]};
        short4v a1 = {wa[4], wa[5], wa[6], wa[7]};
        short4v c0 = {wb[0], wb[1], wb[2], wb[3]};
        short4v c1 = {wb[4], wb[5], wb[6], wb[7]};
        o[2*dp]     = mfma16(a0, pb0, o[2*dp]);
        o[2*dp + 1] = mfma16(a1, pb0, o[2*dp + 1]);
        o[2*dp]     = mfma16(c0, pb1, o[2*dp]);
        o[2*dp + 1] = mfma16(c1, pb1, o[2*dp + 1]);
      }
    }
    __syncthreads();   // all waves done reading before restage/merge
  }

  // ---- in-block 4-way (m,l,o) merge via LDS ----
  if (lg == 0) { lds[8448 + w * 16 + lq] = m; lds[8512 + w * 16 + lq] = l; }
  __syncthreads();
  float M = -1e30f;
#pragma unroll
  for (int i = 0; i < 4; ++i) M = fmaxf(M, lds[8448 + i * 16 + lq]);
  float scale = __expf(m - M);
#pragma unroll
  for (int dt = 0; dt < 8; ++dt) {
    floatx4 so = o[dt] * scale;
    *(floatx4*)&lds[w * 2112 + lq * 132 + dt * 16 + lg * 4] = so;
  }
  __syncthreads();
  // final reduce + normalize + write: thread t -> row t>>4, d0 = (t&15)*8
  {
    int row = tid >> 4, d0 = (tid & 15) * 8;
    float M2 = -1e30f;
#pragma unroll
    for (int i = 0; i < 4; ++i) M2 = fmaxf(M2, lds[8448 + i * 16 + row]);
    float den = 0.f;
#pragma unroll
    for (int i = 0; i < 4; ++i)
      den += __expf(lds[8448 + i * 16 + row] - M2) * lds[8512 + i * 16 + row];
    float inv = 1.0f / den;
    short8 ov;
#pragma unroll
    for (int k = 0; k < 8; ++k) {
      float s = 0.f;
#pragma unroll
      for (int i = 0; i < 4; ++i) s += lds[i * 2112 + row * 132 + d0 + k];
      ov[k] = (short)f2bf(s * inv);
    }
    *(short8*)(comb + (size_t)(q0 + row) * NCOL2 + h * HD + d0) = ov;
  }
}

extern "C" void kernel_launch(void* const* d_in, const int* in_sizes, int n_in,
                              void* d_out, int out_size, void* d_ws, size_t ws_size,
                              hipStream_t stream) {
  (void)in_sizes; (void)n_in; (void)out_size; (void)ws_size;
  const float* x     = (const float*)d_in[0];
  const float* ages  = (const float*)d_in[1];
  const float* sinp  = (const float*)d_in[2];
  const float* cosp  = (const float*)d_in[3];
  const float* bias  = (const float*)d_in[4];
  const float* normw = (const float*)d_in[5];
  const float* w_in  = (const float*)d_in[6];
  const float* b_in  = (const float*)d_in[7];
  const float* w_out = (const float*)d_in[8];
  const float* b_out = (const float*)d_in[9];

  char* ws = (char*)d_ws;
  const size_t SZ_XN   = (size_t)T_DIM * H_DIM * 2;      //  8 MiB
  const size_t SZ_W1T  = (size_t)NCOL1 * H_DIM * 2;      //  88 MiB
  const size_t SZ_T    = (size_t)T_DIM * NCOL1 * 2;      //  88 MiB
  const size_t SZ_HEAD = (size_t)NH * T_DIM * HD * 2;    //   8 MiB
  u16* xn   = (u16*)(ws);
  u16* w1t  = (u16*)(ws + SZ_XN);
  u16* tb   = (u16*)(ws + SZ_XN + SZ_W1T);
  u16* qb   = (u16*)(ws + SZ_XN + SZ_W1T + SZ_T);
  u16* kf   = (u16*)(ws + SZ_XN + SZ_W1T + SZ_T + SZ_HEAD);
  u16* vf   = (u16*)(ws + SZ_XN + SZ_W1T + SZ_T + 2 * SZ_HEAD);
  u16* w2t  = (u16*)(ws + SZ_XN);                  // reuse w1t region (dead after GEMM1)
  u16* comb = (u16*)(ws + SZ_XN + (48ull << 20));  // also inside w1t region, disjoint from w2t

  rmsnorm_k<<<T_DIM, 256, 0, stream>>>(x, ages, normw, xn);
  transpose_f32_bf16<<<dim3(NCOL1 / 32, H_DIM / 32), 256, 0, stream>>>(w_in, w1t, H_DIM, NCOL1);
  gemm_bt<0><<<(T_DIM / 128) * (NCOL1 / 128), 256, 0, stream>>>(xn, w1t, b_in, tb, T_DIM, NCOL1, H_DIM);
  rope_split<<<dim3(T_DIM / 32, NH), 256, 0, stream>>>(tb, sinp, cosp, qb, kf, vf);
  silu_mul<<<(T_DIM * I_DIM) / (256 * 8), 256, 0, stream>>>(tb, comb);
  transpose_f32_bf16<<<dim3(H_DIM / 32, NCOL2 / 32), 256, 0, stream>>>(w_out, w2t, NCOL2, H_DIM);
  attn_fused<<<NH * (T_DIM / 16), 256, 0, stream>>>(qb, kf, vf, bias, comb);
  gemm_bt<1><<<(T_DIM / 128) * (H_DIM / 128), 256, 0, stream>>>(comb, w2t, b_out, d_out, T_DIM, H_DIM, NCOL2);
}

// Round 6
// 603.314 us; speedup vs baseline: 1.6822x; 1.2084x over previous
//
#include <hip/hip_runtime.h>
#include <stdint.h>

typedef unsigned short u16;
typedef __attribute__((ext_vector_type(8))) short short8;
typedef __attribute__((ext_vector_type(4))) short short4v;
typedef __attribute__((ext_vector_type(4))) float floatx4;

#define T_DIM 2048
#define NH    16
#define HD    128
#define H_DIM 2048
#define I_DIM 8192
#define NCOL1 22528   // 3H + 2I
#define NCOL2 10240   // H + I
#define PADW  1036    // LDS words per bias row (1024 + pad; %4==0, 2-way banks)
#define KSPLIT 4
#define KSLEN  (NCOL2 / KSPLIT)   // 2560

__device__ __forceinline__ float bf2f(u16 b) {
  union { uint32_t u; float f; } x; x.u = ((uint32_t)b) << 16; return x.f;
}
__device__ __forceinline__ u16 f2bf(float f) {
  union { float f; uint32_t u; } x; x.f = f;
  uint32_t r = x.u + 0x7fffu + ((x.u >> 16) & 1u);
  return (u16)(r >> 16);
}

__device__ __forceinline__ void gl_lds16(const void* g, void* l) {
  __builtin_amdgcn_global_load_lds((const __attribute__((address_space(1))) void*)g,
                                   (__attribute__((address_space(3))) void*)l, 16, 0, 0);
}

__device__ __forceinline__ floatx4 mfma32(short8 a, short8 b, floatx4 c) {
  return __builtin_amdgcn_mfma_f32_16x16x32_bf16(a, b, c, 0, 0, 0);
}
__device__ __forceinline__ floatx4 mfma16(short4v a, short4v b, floatx4 c) {
#if __has_builtin(__builtin_amdgcn_mfma_f32_16x16x16bf16_1k)
  return __builtin_amdgcn_mfma_f32_16x16x16bf16_1k(a, b, c, 0, 0, 0);
#else
  asm volatile("v_mfma_f32_16x16x16_bf16 %0, %1, %2, %0" : "+v"(c) : "v"(a), "v"(b));
  return c;
#endif
}

// ---------------- RMSNorm + age override -> bf16 ----------------
__global__ __launch_bounds__(256) void rmsnorm_k(
    const float* __restrict__ x, const float* __restrict__ ages,
    const float* __restrict__ w, u16* __restrict__ xn) {
  int t = blockIdx.x, tid = threadIdx.x;
  const float* xr = x + (size_t)t * H_DIM;
  floatx4 a = *(const floatx4*)(xr + tid * 8);
  floatx4 b = *(const floatx4*)(xr + tid * 8 + 4);
  float ss = a[0]*a[0]+a[1]*a[1]+a[2]*a[2]+a[3]*a[3]
           + b[0]*b[0]+b[1]*b[1]+b[2]*b[2]+b[3]*b[3];
#pragma unroll
  for (int off = 32; off >= 1; off >>= 1) ss += __shfl_xor(ss, off);
  __shared__ float red[4];
  if ((tid & 63) == 0) red[tid >> 6] = ss;
  __syncthreads();
  float tot = red[0] + red[1] + red[2] + red[3];
  float rms = rsqrtf(tot * (1.0f / H_DIM) + 1e-6f);
  const float* wr = w + tid * 8;
  float v[8] = {a[0],a[1],a[2],a[3],b[0],b[1],b[2],b[3]};
  short8 o;
#pragma unroll
  for (int i = 0; i < 8; ++i) o[i] = (short)f2bf(v[i] * rms * wr[i]);
  if (tid == 255) {           // covers cols 2040..2047
    float ag = ages[t];
    o[6] = (short)f2bf(ag);
    o[7] = (short)f2bf(ag * ag);
  }
  *(short8*)(xn + (size_t)t * H_DIM + tid * 8) = o;
}

// ------------- fp32 (K,N) -> bf16 (N,K) transpose ---------------
__global__ __launch_bounds__(256) void transpose_f32_bf16(
    const float* __restrict__ in, u16* __restrict__ out, int K, int N) {
  __shared__ float tile[32][33];
  int n0 = blockIdx.x * 32, k0 = blockIdx.y * 32;
  int c = threadIdx.x & 31, r = threadIdx.x >> 5;
#pragma unroll
  for (int i = 0; i < 4; ++i) {
    int kk = r + i * 8;
    tile[c][kk] = in[(size_t)(k0 + kk) * N + n0 + c];
  }
  __syncthreads();
#pragma unroll
  for (int i = 0; i < 4; ++i) {
    int nn = r + i * 8;
    out[(size_t)(n0 + nn) * K + k0 + c] = f2bf(tile[nn][c]);
  }
}

// ------------- bf16 GEMM, B^T (N-major) input, 128x128 tile ------
// OUTF: 0 -> bf16 out + bias, 1 -> f32 out + bias, 2 -> f32 split-K partial
// (no bias; partial sp written at Cout + sp*M*N). klen = K per split.
// Block ordering: bn-major (consecutive blocks share the same B panel).
template<int OUTF>
__global__ __launch_bounds__(256, 2) void gemm_bt(
    const u16* __restrict__ A, const u16* __restrict__ B,
    const float* __restrict__ bias, void* __restrict__ Cout,
    int M, int N, int K, int klen) {
  __shared__ u16 As[4096];
  __shared__ u16 Bs[4096];
  int nbm = M >> 7, nbn = N >> 7;
  int per = nbm * nbn;
  int nwg = per * (K / klen);
  int bid = blockIdx.x;
  int swz = (bid & 7) * (nwg >> 3) + (bid >> 3);   // XCD swizzle (nwg%8==0)
  int sp = swz / per, r = swz % per;
  int bn = r / nbm, bm = r % nbm;                  // bn-major
  int kbeg = sp * klen;
  int tid = threadIdx.x, lane = tid & 63;
  int wr = tid >> 7, wc = (tid >> 6) & 1;
  int lq = lane & 15, lg = lane >> 4;

  int r0 = tid >> 2, kc0 = (tid & 3) << 3;
  const u16* Ag0 = A + (size_t)(bm * 128 + r0) * K + kc0;
  const u16* Ag1 = Ag0 + (size_t)64 * K;
  const u16* Bg0 = B + (size_t)(bn * 128 + r0) * K + kc0;
  const u16* Bg1 = Bg0 + (size_t)64 * K;
  u16* As0 = As + tid * 8;
  u16* As1 = As + 2048 + tid * 8;
  u16* Bs0 = Bs + tid * 8;
  u16* Bs1 = Bs + 2048 + tid * 8;

  const u16* Ard = As + (wr * 64 + lq) * 32 + lg * 8;
  const u16* Brd = Bs + (wc * 64 + lq) * 32 + lg * 8;

  floatx4 acc[4][4] = {};

  for (int kt = kbeg; kt < kbeg + klen; kt += 32) {
    __syncthreads();
    gl_lds16(Ag0 + kt, As0);
    gl_lds16(Ag1 + kt, As1);
    gl_lds16(Bg0 + kt, Bs0);
    gl_lds16(Bg1 + kt, Bs1);
    __syncthreads();
    short8 af[4], bfr[4];
#pragma unroll
    for (int i = 0; i < 4; ++i) af[i]  = *(const short8*)(Ard + i * 512);
#pragma unroll
    for (int i = 0; i < 4; ++i) bfr[i] = *(const short8*)(Brd + i * 512);
#pragma unroll
    for (int mi = 0; mi < 4; ++mi)
#pragma unroll
      for (int ni = 0; ni < 4; ++ni)
        acc[mi][ni] = mfma32(af[mi], bfr[ni], acc[mi][ni]);
  }

#pragma unroll
  for (int mi = 0; mi < 4; ++mi) {
#pragma unroll
    for (int ni = 0; ni < 4; ++ni) {
      int col = bn * 128 + wc * 64 + ni * 16 + lq;
      float bv = (OUTF == 2) ? 0.f : bias[col];
#pragma unroll
      for (int j = 0; j < 4; ++j) {
        int row = bm * 128 + wr * 64 + mi * 16 + lg * 4 + j;
        float vv = acc[mi][ni][j] + bv;
        if (OUTF == 0)      ((u16*)Cout)[(size_t)row * N + col] = f2bf(vv);
        else if (OUTF == 1) ((float*)Cout)[(size_t)row * N + col] = vv;
        else ((float*)Cout)[(size_t)sp * M * N + (size_t)row * N + col] = vv;
      }
    }
  }
}

// ---- reduce split-K partials + bias -> f32 out ------------------
__global__ __launch_bounds__(256) void reduce_split(
    const float* __restrict__ part, const float* __restrict__ bias,
    float* __restrict__ out) {
  size_t idx = ((size_t)blockIdx.x * 256 + threadIdx.x) * 4;
  int col = (int)(idx & (H_DIM - 1));
  floatx4 acc = *(const floatx4*)(bias + col);
#pragma unroll
  for (int s = 0; s < KSPLIT; ++s) {
    floatx4 p = *(const floatx4*)(part + (size_t)s * T_DIM * H_DIM + idx);
#pragma unroll
    for (int j = 0; j < 4; ++j) acc[j] += p[j];
  }
  *(floatx4*)(out + idx) = acc;
}

// ---- RoPE on q,k; split qkv; K,V stored in MFMA-fragment order ----
// K_frag chunk (h, s16, t): 64 lanes x 8 elems; lane=(s&15)+16*lg holds
//   K[s16*16+(s&15)][t*32+lg*8+j], j=0..7.  chunk = 512 elems (1KB).
// V_frag chunk (h, s16, dp): lane=(d&15)+16*lg holds
//   V[s16*16+lg*4+j][dp*32+par*16+(d&15)] packed [par=0:4elem][par=1:4elem].
__global__ __launch_bounds__(256) void rope_split(
    const u16* __restrict__ tb, const float* __restrict__ sinp, const float* __restrict__ cosp,
    u16* __restrict__ qb, u16* __restrict__ kf, u16* __restrict__ vf) {
  __shared__ u16 vtile[32][130];
  int t0 = blockIdx.x * 32, h = blockIdx.y, tid = threadIdx.x;
  int r = tid >> 3, d0 = (tid & 7) << 4;
  int t = t0 + r;
  const u16* base = tb + (size_t)t * NCOL1 + 2 * I_DIM + h * HD + d0;
  const float* cp = cosp + (size_t)t * HD + d0;
  const float* sp = sinp + (size_t)t * HD + d0;
  float cv[16], sv[16];
#pragma unroll
  for (int i = 0; i < 16; i += 4) {
    *(floatx4*)(cv + i) = *(const floatx4*)(cp + i);
    *(floatx4*)(sv + i) = *(const floatx4*)(sp + i);
  }
#pragma unroll
  for (int s = 0; s < 2; ++s) {
    const u16* src = base + s * (NH * HD);
    short8 x0 = *(const short8*)src;
    short8 x1 = *(const short8*)(src + 8);
    float xf[16];
#pragma unroll
    for (int i = 0; i < 8; ++i) { xf[i] = bf2f((u16)x0[i]); xf[8 + i] = bf2f((u16)x1[i]); }
    short8 o0, o1;
#pragma unroll
    for (int i = 0; i < 8; i += 2) {
      o0[i]     = (short)f2bf(xf[i] * cv[i] - xf[i + 1] * sv[i]);
      o0[i + 1] = (short)f2bf(xf[i + 1] * cv[i + 1] + xf[i] * sv[i + 1]);
      o1[i]     = (short)f2bf(xf[8 + i] * cv[8 + i] - xf[9 + i] * sv[8 + i]);
      o1[i + 1] = (short)f2bf(xf[9 + i] * cv[9 + i] + xf[8 + i] * sv[9 + i]);
    }
    if (s == 0) {
      u16* dst = qb + ((size_t)h * T_DIM + t) * HD + d0;
      *(short8*)dst = o0;
      *(short8*)(dst + 8) = o1;
    } else {
      int s16 = t >> 4, tt = d0 >> 5, lg0 = (d0 >> 3) & 3;
      size_t cb = (((size_t)h * 128 + s16) * 4 + tt) * 512 + ((t & 15) + 16 * lg0) * 8;
      *(short8*)(kf + cb) = o0;          // lg0
      *(short8*)(kf + cb + 128) = o1;    // lg0+1
    }
  }
  short8 v0 = *(const short8*)(base + 2 * NH * HD);
  short8 v1 = *(const short8*)(base + 2 * NH * HD + 8);
#pragma unroll
  for (int i = 0; i < 8; ++i) {
    vtile[r][d0 + i]     = (u16)v0[i];
    vtile[r][d0 + 8 + i] = (u16)v1[i];
  }
  __syncthreads();
  {
    int d = tid >> 1, th = (tid & 1) << 4;
    int s16 = (t0 + th) >> 4;
    int dp = d >> 5, par = (d >> 4) & 1, lqv = d & 15;
    size_t cb = (((size_t)h * 128 + s16) * 4 + dp) * 512 + par * 4;
#pragma unroll
    for (int lg = 0; lg < 4; ++lg) {
      short4v g;
#pragma unroll
      for (int j = 0; j < 4; ++j) g[j] = (short)vtile[th + lg * 4 + j][d];
      *(short4v*)(vf + cb + (size_t)(lqv + 16 * lg) * 8) = g;
    }
  }
}

// -------------------- silu(x1)*x2 -> comb[:, H:] -----------------
__global__ __launch_bounds__(256) void silu_mul(
    const u16* __restrict__ tb, u16* __restrict__ comb) {
  int idx = blockIdx.x * 256 + threadIdx.x;
  int t = idx >> 10;
  int j = (idx & 1023) << 3;
  const u16* p1 = tb + (size_t)t * NCOL1 + j;
  const u16* p2 = p1 + I_DIM;
  short8 a = *(const short8*)p1;
  short8 b = *(const short8*)p2;
  short8 o;
#pragma unroll
  for (int i = 0; i < 8; ++i) {
    float x1 = bf2f((u16)a[i]), x2 = bf2f((u16)b[i]);
    float s = x1 / (1.0f + __expf(-x1));
    o[i] = (short)f2bf(s * x2);
  }
  *(short8*)(comb + (size_t)t * NCOL2 + H_DIM + j) = o;
}

// ---- fused flash attention; bias dense in LDS; K/V fragment-packed ----
__global__ __launch_bounds__(256) void attn_fused(
    const u16* __restrict__ Q, const u16* __restrict__ kf,
    const u16* __restrict__ vf, const float* __restrict__ bias,
    u16* __restrict__ comb) {
  __shared__ float lds[16 * PADW];   // 66,304 B; reused for the final merge
  int bid = blockIdx.x;
  int swz = (bid & 7) * 256 + (bid >> 3);   // 2048 blocks, bijective XCD swizzle
  int h = swz >> 7, qt = swz & 127;
  int q0 = qt * 16;
  int tid = threadIdx.x;
  int w = tid >> 6, lane = tid & 63;
  int lq = lane & 15, lg = lane >> 4;

  const u16* Qp = Q + ((size_t)h * T_DIM + q0 + lq) * HD + lg * 8;
  const u16* Kf = kf + ((size_t)h * 128) * 2048 + lane * 8;  // + s16*2048 + t*512
  const u16* Vf = vf + ((size_t)h * 128) * 2048 + lane * 8;  // + s16*2048 + dp*512
  const float* Bh = bias + ((size_t)h * T_DIM + q0) * T_DIM;

  short8 qf[4];
#pragma unroll
  for (int t = 0; t < 4; ++t) qf[t] = *(const short8*)(Qp + t * 32);

  floatx4 o[8] = {};
  float m = -1e30f, l = 0.f;
  const float sc = 0.08838834764831845f;   // 1/sqrt(128)

#pragma unroll
  for (int tile = 0; tile < 2; ++tile) {
    // ---- stage bias tile: 16 rows x 4KB contiguous each ----
#pragma unroll
    for (int r = 0; r < 16; ++r) {
      const float* src = Bh + (size_t)r * T_DIM + tile * 1024 + tid * 4;
      gl_lds16(src, &lds[r * PADW + tid * 4]);
    }
    __syncthreads();   // drains vmcnt -> tile resident
    // ---- each wave: 8 sub-bodies of 32 s, strided by 128 ----
#pragma unroll
    for (int sub = 0; sub < 8; ++sub) {
      int soff = sub * 128 + w * 32;          // offset within tile
      int s0 = tile * 1024 + soff;            // global s
      int s16a = s0 >> 4;
      const u16* ka = Kf + (size_t)s16a * 2048;
      floatx4 st0 = {0.f,0.f,0.f,0.f}, st1 = {0.f,0.f,0.f,0.f};
#pragma unroll
      for (int t = 0; t < 4; ++t) {
        st0 = mfma32(*(const short8*)(ka + t * 512), qf[t], st0);
        st1 = mfma32(*(const short8*)(ka + 2048 + t * 512), qf[t], st1);
      }
      floatx4 b0 = *(const floatx4*)&lds[lq * PADW + soff + lg * 4];
      floatx4 b1 = *(const floatx4*)&lds[lq * PADW + soff + lg * 4 + 16];
      float p[8]; float tmax = -1e30f;
#pragma unroll
      for (int j = 0; j < 4; ++j) {
        p[j]     = st0[j] * sc + b0[j];
        p[4 + j] = st1[j] * sc + b1[j];
        tmax = fmaxf(tmax, fmaxf(p[j], p[4 + j]));
      }
      tmax = fmaxf(tmax, __shfl_xor(tmax, 16));
      tmax = fmaxf(tmax, __shfl_xor(tmax, 32));
      float mn = fmaxf(m, tmax);
      float alpha = __expf(m - mn);
      float rs = 0.f;
      short4v pb0, pb1;
#pragma unroll
      for (int j = 0; j < 4; ++j) {
        float e0 = __expf(p[j] - mn), e1 = __expf(p[4 + j] - mn);
        rs += e0 + e1;
        pb0[j] = (short)f2bf(e0);
        pb1[j] = (short)f2bf(e1);
      }
      rs += __shfl_xor(rs, 16);
      rs += __shfl_xor(rs, 32);
      l = l * alpha + rs; m = mn;
#pragma unroll
      for (int dt = 0; dt < 8; ++dt) o[dt] *= alpha;
      const u16* vb = Vf + (size_t)s16a * 2048;
#pragma unroll
      for (int dp = 0; dp < 4; ++dp) {
        short8 wa = *(const short8*)(vb + dp * 512);
        short8 wb = *(const short8*)(vb + 2048 + dp * 512);
        short4v a0 = {wa[0], wa[1], wa[2], wa[3]};
        short4v a1 = {wa[4], wa[5], wa[6], wa[7]};
        short4v c0 = {wb[0], wb[1], wb[2], wb[3]};
        short4v c1 = {wb[4], wb[5], wb[6], wb[7]};
        o[2*dp]     = mfma16(a0, pb0, o[2*dp]);
        o[2*dp + 1] = mfma16(a1, pb0, o[2*dp + 1]);
        o[2*dp]     = mfma16(c0, pb1, o[2*dp]);
        o[2*dp + 1] = mfma16(c1, pb1, o[2*dp + 1]);
      }
    }
    __syncthreads();   // all waves done reading before restage/merge
  }

  // ---- in-block 4-way (m,l,o) merge via LDS ----
  if (lg == 0) { lds[8448 + w * 16 + lq] = m; lds[8512 + w * 16 + lq] = l; }
  __syncthreads();
  float M = -1e30f;
#pragma unroll
  for (int i = 0; i < 4; ++i) M = fmaxf(M, lds[8448 + i * 16 + lq]);
  float scale = __expf(m - M);
#pragma unroll
  for (int dt = 0; dt < 8; ++dt) {
    floatx4 so = o[dt] * scale;
    *(floatx4*)&lds[w * 2112 + lq * 132 + dt * 16 + lg * 4] = so;
  }
  __syncthreads();
  // final reduce + normalize + write: thread t -> row t>>4, d0 = (t&15)*8
  {
    int row = tid >> 4, d0 = (tid & 15) * 8;
    float M2 = -1e30f;
#pragma unroll
    for (int i = 0; i < 4; ++i) M2 = fmaxf(M2, lds[8448 + i * 16 + row]);
    float den = 0.f;
#pragma unroll
    for (int i = 0; i < 4; ++i)
      den += __expf(lds[8448 + i * 16 + row] - M2) * lds[8512 + i * 16 + row];
    float inv = 1.0f / den;
    short8 ov;
#pragma unroll
    for (int k = 0; k < 8; ++k) {
      float s = 0.f;
#pragma unroll
      for (int i = 0; i < 4; ++i) s += lds[i * 2112 + row * 132 + d0 + k];
      ov[k] = (short)f2bf(s * inv);
    }
    *(short8*)(comb + (size_t)(q0 + row) * NCOL2 + h * HD + d0) = ov;
  }
}

extern "C" void kernel_launch(void* const* d_in, const int* in_sizes, int n_in,
                              void* d_out, int out_size, void* d_ws, size_t ws_size,
                              hipStream_t stream) {
  (void)in_sizes; (void)n_in; (void)out_size; (void)ws_size;
  const float* x     = (const float*)d_in[0];
  const float* ages  = (const float*)d_in[1];
  const float* sinp  = (const float*)d_in[2];
  const float* cosp  = (const float*)d_in[3];
  const float* bias  = (const float*)d_in[4];
  const float* normw = (const float*)d_in[5];
  const float* w_in  = (const float*)d_in[6];
  const float* b_in  = (const float*)d_in[7];
  const float* w_out = (const float*)d_in[8];
  const float* b_out = (const float*)d_in[9];

  char* ws = (char*)d_ws;
  const size_t SZ_XN   = (size_t)T_DIM * H_DIM * 2;      //  8 MiB
  const size_t SZ_W1T  = (size_t)NCOL1 * H_DIM * 2;      //  88 MiB
  const size_t SZ_T    = (size_t)T_DIM * NCOL1 * 2;      //  88 MiB
  const size_t SZ_HEAD = (size_t)NH * T_DIM * HD * 2;    //   8 MiB
  u16* xn   = (u16*)(ws);
  u16* w1t  = (u16*)(ws + SZ_XN);
  u16* tb   = (u16*)(ws + SZ_XN + SZ_W1T);
  u16* qb   = (u16*)(ws + SZ_XN + SZ_W1T + SZ_T);
  u16* kf   = (u16*)(ws + SZ_XN + SZ_W1T + SZ_T + SZ_HEAD);
  u16* vf   = (u16*)(ws + SZ_XN + SZ_W1T + SZ_T + 2 * SZ_HEAD);
  u16* w2t  = (u16*)(ws + SZ_XN);                  // reuse w1t region (dead after GEMM1)
  u16* comb = (u16*)(ws + SZ_XN + (48ull << 20));  // also inside w1t region, disjoint from w2t
  float* part = (float*)tb;                        // split-K partials (64 MiB) in dead tb region

  rmsnorm_k<<<T_DIM, 256, 0, stream>>>(x, ages, normw, xn);
  transpose_f32_bf16<<<dim3(NCOL1 / 32, H_DIM / 32), 256, 0, stream>>>(w_in, w1t, H_DIM, NCOL1);
  gemm_bt<0><<<(T_DIM / 128) * (NCOL1 / 128), 256, 0, stream>>>(
      xn, w1t, b_in, tb, T_DIM, NCOL1, H_DIM, H_DIM);
  rope_split<<<dim3(T_DIM / 32, NH), 256, 0, stream>>>(tb, sinp, cosp, qb, kf, vf);
  silu_mul<<<(T_DIM * I_DIM) / (256 * 8), 256, 0, stream>>>(tb, comb);
  transpose_f32_bf16<<<dim3(H_DIM / 32, NCOL2 / 32), 256, 0, stream>>>(w_out, w2t, NCOL2, H_DIM);
  attn_fused<<<NH * (T_DIM / 16), 256, 0, stream>>>(qb, kf, vf, bias, comb);
  gemm_bt<2><<<(T_DIM / 128) * (H_DIM / 128) * KSPLIT, 256, 0, stream>>>(
      comb, w2t, b_out, part, T_DIM, H_DIM, NCOL2, KSLEN);
  reduce_split<<<(T_DIM * H_DIM / 4) / 256, 256, 0, stream>>>(part, b_out, (float*)d_out);
}